// Round 4
// baseline (217.491 us; speedup 1.0000x reference)
//
#include <hip/hip_runtime.h>
#include <hip/hip_bf16.h>

// ConformerAttention on MI355X (gfx950), bf16 MFMA internal, fp32 in/out.
// rel_shift(ps)[i,j] == ps[i, j-i+S-1]  -> banded pos-score, never materialize [S,P].
// R11: attn — R9's single-barrier dbuf schedule (proven 62.5us) + compact
//      XOR-swizzled P tile (LDS 41984->40960 B => 4 blocks/CU, grid co-resident)
//      + head-pinned XCD swizzle (h = bid&7: pos panel L2-resident per XCD,
//      K/V working set 2.25MB < 4MB L2, disjoint full-line a_bf writes).

typedef __attribute__((ext_vector_type(8))) short  s16x8;
typedef __attribute__((ext_vector_type(8))) __bf16 bfv8;
typedef __attribute__((ext_vector_type(4))) float  f32x4;
typedef __attribute__((ext_vector_type(4))) unsigned u32x4;

__device__ __forceinline__ float b2f(short s){
  unsigned u = ((unsigned)(unsigned short)s) << 16;
  float f; __builtin_memcpy(&f, &u, 4); return f;
}
__device__ __forceinline__ short f2b(float f){
  unsigned u; __builtin_memcpy(&u, &f, 4);
  u = (u + 0x7fffu + ((u >> 16) & 1u)) >> 16;
  return (short)u;
}
// packed 2xf32 -> 2xbf16 (v_cvt_pk_bf16_f32 on gfx950), low = first arg
__device__ __forceinline__ unsigned pk2(float lo, float hi){
  __hip_bfloat162 t = __float22bfloat162_rn(make_float2(lo, hi));
  unsigned u; __builtin_memcpy(&u, &t, 4); return u;
}
__device__ __forceinline__ f32x4 MFMA(s16x8 a, s16x8 b, f32x4 c){
  return __builtin_amdgcn_mfma_f32_16x16x32_bf16(
      __builtin_bit_cast(bfv8, a), __builtin_bit_cast(bfv8, b), c, 0, 0, 0);
}
__device__ __forceinline__ void gload_lds16(const void* g, void* l){
  __builtin_amdgcn_global_load_lds(
      (const __attribute__((address_space(1))) void*)g,
      (__attribute__((address_space(3))) void*)l, 16, 0, 0);
}
__device__ __forceinline__ void cvt8(const float* in, short* out, size_t i8){
  f32x4 a = *(const f32x4*)(in + i8*8);
  f32x4 b = *(const f32x4*)(in + i8*8 + 4);
  u32x4 o;
  o[0] = pk2(a[0],a[1]); o[1] = pk2(a[2],a[3]);
  o[2] = pk2(b[0],b[1]); o[3] = pk2(b[2],b[3]);
  *(u32x4*)(out + i8*8) = o;
}

// ---- prep: weight/pos converts + LayerNorm, one launch ----
__global__ __launch_bounds__(256) void prep_kernel(
    const float* __restrict__ Wq, const float* __restrict__ Wk,
    const float* __restrict__ Wv, const float* __restrict__ Wo,
    const float* __restrict__ Wp, const float* __restrict__ pos,
    const float* __restrict__ x, const float* __restrict__ lnw, const float* __restrict__ lnb,
    short* __restrict__ wqkv, short* __restrict__ wo, short* __restrict__ wp,
    short* __restrict__ posbf, short* __restrict__ h_bf)
{
  int bid = blockIdx.x, tid = threadIdx.x;
  if(bid < 640){
    int w = bid >> 7;
    size_t i = (size_t)(bid & 127)*256 + tid;
    const float* src; short* dst;
    if(w == 0){ src = Wq; dst = wqkv; }
    else if(w == 1){ src = Wk; dst = wqkv + 262144; }
    else if(w == 2){ src = Wv; dst = wqkv + 524288; }
    else if(w == 3){ src = Wo; dst = wo; }
    else { src = Wp; dst = wp; }
    cvt8(src, dst, i);
  } else if(bid < 1152){
    size_t i = (size_t)(bid - 640)*256 + tid;
    if(i < 131008) cvt8(pos, posbf, i);        // 2047*512/8
  } else {
    int row = (bid - 1152)*4 + (tid >> 6);
    int lane = tid & 63;
    const float* xr = x + (size_t)row*512;
    f32x4 v0 = *(const f32x4*)(xr + lane*8);
    f32x4 v1 = *(const f32x4*)(xr + lane*8 + 4);
    float s  = v0[0]+v0[1]+v0[2]+v0[3]+v1[0]+v1[1]+v1[2]+v1[3];
    float s2 = v0[0]*v0[0]+v0[1]*v0[1]+v0[2]*v0[2]+v0[3]*v0[3]
             + v1[0]*v1[0]+v1[1]*v1[1]+v1[2]*v1[2]+v1[3]*v1[3];
    #pragma unroll
    for(int m=1;m<64;m<<=1){ s += __shfl_xor(s,m); s2 += __shfl_xor(s2,m); }
    float mu = s * (1.0f/512.0f);
    float rs = rsqrtf(s2*(1.0f/512.0f) - mu*mu + 1e-5f);
    float y[8];
    #pragma unroll
    for(int e=0;e<8;e++){
      float xv = (e<4)? v0[e] : v1[e-4];
      int d = lane*8 + e;
      y[e] = (xv - mu)*rs*lnw[d] + lnb[d];
    }
    u32x4 o;
    o[0]=pk2(y[0],y[1]); o[1]=pk2(y[2],y[3]); o[2]=pk2(y[4],y[5]); o[3]=pk2(y[6],y[7]);
    *(u32x4*)(h_bf + (size_t)row*512 + lane*8) = o;
  }
}

// ---- fused QKV GEMM (768 blocks, 128x128) + pos GEMM (256 blocks, 64x64) ----
__global__ __launch_bounds__(256) void gemm_fused(
    const short* __restrict__ h_bf, const short* __restrict__ wqkv,
    const float* __restrict__ bq, const float* __restrict__ bk, const float* __restrict__ bv,
    const short* __restrict__ posbf, const short* __restrict__ wp,
    short* __restrict__ q_sw, short* __restrict__ k_sw, short* __restrict__ v_sw,
    short* __restrict__ p_sw)
{
  __shared__ __align__(16) short smem[9216];   // At|Bt staging, then C-tile staging
  short* At = smem;
  short* Bt = smem + 4096;
  int bid = blockIdx.x, tid = threadIdx.x;
  int wave = tid >> 6, lane = tid & 63;
  int quad = lane >> 4, l16 = lane & 15;
  int srow = lane >> 2, scol = (lane & 3)*8;
  if(bid < 768){
    int bx = bid % 12, by = bid / 12;
    int m0 = by*128, n0 = bx*128;
    int wm = wave >> 1, wn = wave & 1;
    f32x4 acc[4][4] = {};
    for(int k0=0; k0<512; k0+=32){
      #pragma unroll
      for(int c=0;c<2;c++){
        int rb = (wave + 4*c)*16;
        gload_lds16(h_bf + (size_t)(m0 + rb + srow)*512 + k0 + scol, At + rb*32);
        gload_lds16(wqkv + (size_t)(n0 + rb + srow)*512 + k0 + scol, Bt + rb*32);
      }
      __syncthreads();
      s16x8 af[4], bfr[4];
      #pragma unroll
      for(int i=0;i<4;i++) af[i]  = *(const s16x8*)(At + (wm*64 + i*16 + l16)*32 + quad*8);
      #pragma unroll
      for(int j=0;j<4;j++) bfr[j] = *(const s16x8*)(Bt + (wn*64 + j*16 + l16)*32 + quad*8);
      #pragma unroll
      for(int i=0;i<4;i++)
        #pragma unroll
        for(int j=0;j<4;j++)
          acc[i][j] = MFMA(af[i], bfr[j], acc[i][j]);
      __syncthreads();
    }
    int seg = bx >> 2;               // 0 q, 1 k, 2 v (uniform per block)
    int nseg = (bx & 3)*128;
    int bb = by >> 3;
    const float* bsrc = (seg==0)? bq : (seg==1)? bk : bv;
    float bias_j[4];
    #pragma unroll
    for(int j=0;j<4;j++) bias_j[j] = bsrc[nseg + wn*64 + j*16 + l16];
    if(seg < 2){
      short* dst = seg ? k_sw : q_sw;
      #pragma unroll
      for(int h2=0; h2<2; h2++){
        if(wm == h2){
          #pragma unroll
          for(int i=0;i<4;i++){
            int lr = i*16 + quad*4;
            #pragma unroll
            for(int j=0;j<4;j++){
              int cl = wn*64 + j*16 + l16;
              unsigned p01 = pk2(acc[i][j][0]+bias_j[j], acc[i][j][1]+bias_j[j]);
              unsigned p23 = pk2(acc[i][j][2]+bias_j[j], acc[i][j][3]+bias_j[j]);
              smem[(lr+0)*136 + cl] = (short)p01;
              smem[(lr+1)*136 + cl] = (short)(p01>>16);
              smem[(lr+2)*136 + cl] = (short)p23;
              smem[(lr+3)*136 + cl] = (short)(p23>>16);
            }
          }
        }
        __syncthreads();
        #pragma unroll
        for(int it=0; it<4; it++){
          int ci = it*4 + wave;              // hs = ci>>2 (head/ks slot), tb = ci&3
          int hs = ci >> 2, tb = ci & 3;
          s16x8 vv = *(const s16x8*)(smem + (tb*16 + l16)*136 + hs*32 + quad*8);
          int hh = (nseg>>6) + (hs>>1);
          int tg = ((m0 + h2*64)>>4) + tb;
          size_t chunk = ((size_t)((bb*8 + hh)*64 + tg))*2 + (hs&1);
          *(s16x8*)(dst + chunk*512 + (size_t)lane*8) = vv;
        }
        __syncthreads();
      }
    } else {
      // V: stage transposed Ct_v[dim 0..127][token 0..63], stride 72
      #pragma unroll
      for(int h2=0; h2<2; h2++){
        int jt = by*2 + h2;
        if(wm == h2){
          #pragma unroll
          for(int i=0;i<4;i++){
            int tl = i*16 + quad*4;
            #pragma unroll
            for(int j=0;j<4;j++){
              int dl = wn*64 + j*16 + l16;
              unsigned p01 = pk2(acc[i][j][0]+bias_j[j], acc[i][j][1]+bias_j[j]);
              unsigned p23 = pk2(acc[i][j][2]+bias_j[j], acc[i][j][3]+bias_j[j]);
              unsigned* w2 = (unsigned*)(smem + dl*72 + tl);
              w2[0] = p01; w2[1] = p23;
            }
          }
        }
        __syncthreads();
        #pragma unroll
        for(int it=0; it<4; it++){
          int ci = it*4 + wave;              // ci = hl*8 + ds*2 + jk
          int hl = ci>>3, ds = (ci>>1)&3, jk = ci&1;
          s16x8 vv = *(const s16x8*)(smem + (hl*64 + ds*16 + l16)*72 + jk*32 + quad*8);
          int hh = (nseg>>6) + hl;
          size_t chunk = (((size_t)((bb*8 + hh)*16 + jt))*4 + ds)*2 + jk;
          *(s16x8*)(v_sw + chunk*512 + (size_t)lane*8) = vv;
        }
        __syncthreads();
      }
    }
  } else {
    // pos projection: [2048,512] = posbf(2047 rows, clamped) @ wp^T, 64x64 tiles
    int pid = bid - 768;
    int bx = pid % 8, by = pid / 8;
    int m0 = by*64, n0 = bx*64;
    int wm = wave >> 1, wn = wave & 1;
    f32x4 acc[2][2] = {};
    for(int k0=0; k0<512; k0+=32){
      int rb = wave*16;
      int ra = m0 + rb + srow; if(ra > 2046) ra = 2046;
      gload_lds16(posbf + (size_t)ra*512 + k0 + scol, At + rb*32);
      gload_lds16(wp + (size_t)(n0 + rb + srow)*512 + k0 + scol, Bt + rb*32);
      __syncthreads();
      s16x8 af[2], bfr[2];
      #pragma unroll
      for(int i=0;i<2;i++) af[i]  = *(const s16x8*)(At + (wm*32 + i*16 + l16)*32 + quad*8);
      #pragma unroll
      for(int j=0;j<2;j++) bfr[j] = *(const s16x8*)(Bt + (wn*32 + j*16 + l16)*32 + quad*8);
      #pragma unroll
      for(int i=0;i<2;i++)
        #pragma unroll
        for(int j=0;j<2;j++)
          acc[i][j] = MFMA(af[i], bfr[j], acc[i][j]);
      __syncthreads();
    }
    #pragma unroll
    for(int i=0;i<2;i++){
      int rowb = m0 + wm*32 + i*16 + quad*4;          // rowb&15 = quad*4
      #pragma unroll
      for(int j=0;j<2;j++){
        int col = n0 + wn*32 + j*16 + l16;
        int hh = col>>6, ks = (col>>5)&1, qd = (col>>3)&3, e = col&7;
        int rblk = rowb>>4;
        size_t base = ((size_t)(((hh*128+rblk)*2+ks)*64) + qd*16)*8 + e;
        #pragma unroll
        for(int r=0;r<4;r++)
          p_sw[base + (size_t)(quad*4+r)*8] = f2b(acc[i][j][r]);
      }
    }
  }
}

// ---- Fused rel-pos attention (R11): flat grid 1024; head-pinned XCD swizzle
// (h = bid&7 -> each XCD keeps one head's 256KB pos panel L2-resident; K/V
// working set ~2.25MB < 4MB per-XCD L2). 4 waves; wave w owns q-rows
// [qt*64 + w*16, +16) and iterates all 16 key tiles. K+V tiles double-buffered
// in LDS via global_load_lds, ONE barrier per jt (R9 schedule). Compact
// XOR-swizzled per-wave P tile (16x64, idx ^ ((row&7)<<3)) -> LDS 40960 B
// -> 4 blocks/CU, whole grid co-resident. Pos fragments register-prefetched
// one jt ahead. Linear (no-max) softmax (exact 0.125 fold, __expf); rotated
// pos-score fed as QK MFMA C-init; denominator via ones-splat PV MFMA.
__global__ __launch_bounds__(256, 4) void attn_kernel(
    const short* __restrict__ q_sw, const short* __restrict__ k_sw,
    const short* __restrict__ v_sw, const short* __restrict__ p_sw,
    const float* __restrict__ bu, const float* __restrict__ bvv,
    short* __restrict__ out)
{
  __shared__ __align__(16) short kv[2][8192];   // [buf][units 0..7 = K | 8..15 = V]
  __shared__ __align__(16) short pwall[4096];   // 4 waves x compact swizzled 16x64
  int tid = threadIdx.x;
  int wave = tid >> 6, lane = tid & 63, quad = lane >> 4, l16 = lane & 15;
  int bid = blockIdx.x;
  int h  = bid & 7;                  // XCD-pinned head
  int qt = (bid >> 3) & 15;
  int b  = bid >> 7;
  int bh = b*8 + h;
  int iblk = qt*4 + wave;            // this wave's 16-row q tile (0..63)
  int iw = iblk*16;
  short* pw = pwall + wave*1024;

  const short* qb = q_sw + (size_t)bh*65536;
  const short* kb = k_sw + (size_t)bh*65536;
  const short* vb = v_sw + (size_t)bh*65536;
  const short* pb = p_sw + (size_t)h*131072;

  // q fragments; bias + exact 0.125 scale folded
  s16x8 qu[2], qv[2];
  #pragma unroll
  for(int ks=0;ks<2;ks++){
    s16x8 qr = *(const s16x8*)(qb + ((size_t)(iblk*2+ks)*64 + lane)*8);
    short tu[8], tv[8];
    #pragma unroll
    for(int e=0;e<8;e++){
      int d = h*64 + ks*32 + quad*8 + e;
      float f = b2f(qr[e]);
      tu[e] = f2b((f + bu[d]) * 0.125f);
      tv[e] = f2b((f + bvv[d]) * 0.125f);
    }
    qu[ks] = *(s16x8*)tu; qv[ks] = *(s16x8*)tv;
  }

  // ones splat for the denominator MFMA (bf16 1.0 = 0x3F80)
  s16x8 ones;
  #pragma unroll
  for(int e=0;e<8;e++) ones[e] = (short)0x3F80;

  // hoisted band-gather controls (per accumulator register r)
  int srcl[4]; bool lo[4];
  #pragma unroll
  for(int r=0;r<4;r++){
    int il = quad*4 + r;
    srcl[r] = quad*16 + ((l16 + 15 - il) & 15);
    lo[r]   = (l16 <= il);
  }

  f32x4 oacc[4] = {};
  f32x4 lacc = {};
  s16x8 Pa[5][2];                    // prefetched pos fragments for current jt

  // cooperative K/V stage: unit = wave*4 + r; units 0..7 = K tile, 8..15 = V tile.
  auto STAGE = [&](int jt, int bufi){
    const short* base = (wave < 2) ? kb : vb;
    #pragma unroll
    for(int r=0;r<4;r++){
      int unit = wave*4 + r;
      gload_lds16(base + (size_t)jt*4096 + (unit&7)*512 + lane*8,
                  &kv[bufi][unit*512]);
    }
  };
  auto LOADPOS = [&](int jt){
    int rb0 = (jt*64 - iw + 1008) >> 4;
    #pragma unroll
    for(int nt=0;nt<5;nt++)
      #pragma unroll
      for(int ks=0;ks<2;ks++)
        Pa[nt][ks] = *(const s16x8*)(pb + (size_t)((rb0+nt)*2+ks)*512 + lane*8);
  };
  auto COMPUTE = [&](const short* Kt, const short* Vt, int next_jt){
    // pos MFMAs consume Pa, then Pa is refilled for next_jt (prefetch window =
    // rest of this iteration's compute).
    f32x4 ps[5];
    __builtin_amdgcn_s_setprio(1);
    #pragma unroll
    for(int nt=0;nt<5;nt++){
      f32x4 a = {};
      a = MFMA(qv[0], Pa[nt][0], a);
      a = MFMA(qv[1], Pa[nt][1], a);
      ps[nt] = a;
    }
    __builtin_amdgcn_s_setprio(0);
    if(next_jt < 16) LOADPOS(next_jt);
    // rotate band lanes
    float rot[4][5];
    #pragma unroll
    for(int r=0;r<4;r++)
      #pragma unroll
      for(int nt=0;nt<5;nt++) rot[r][nt] = __shfl(ps[nt][r], srcl[r]);
    // content scores with rotated pos-score as C-init; exp; P->LDS (swizzled)
    #pragma unroll
    for(int js=0;js<4;js++){
      s16x8 kf0 = *(const s16x8*)(Kt + (js*2+0)*512 + lane*8);
      s16x8 kf1 = *(const s16x8*)(Kt + (js*2+1)*512 + lane*8);
      f32x4 c0;
      #pragma unroll
      for(int r=0;r<4;r++) c0[r] = lo[r] ? rot[r][js] : rot[r][js+1];
      f32x4 a = MFMA(qu[0], kf0, c0);
      a = MFMA(qu[1], kf1, a);
      int col = js*16 + l16;
      unsigned p01 = pk2(__expf(a[0]), __expf(a[1]));
      unsigned p23 = pk2(__expf(a[2]), __expf(a[3]));
      int r0 = quad*4;
      pw[((r0+0)*64 + col) ^ (((r0+0)&7)<<3)] = (short)p01;
      pw[((r0+1)*64 + col) ^ (((r0+1)&7)<<3)] = (short)(p01>>16);
      pw[((r0+2)*64 + col) ^ (((r0+2)&7)<<3)] = (short)p23;
      pw[((r0+3)*64 + col) ^ (((r0+3)&7)<<3)] = (short)(p23>>16);
    }
    // PV: 2 j-ksteps x (4 d-subtiles + ones row-sum); swizzled P reads
    __builtin_amdgcn_s_setprio(1);
    #pragma unroll
    for(int jk=0;jk<2;jk++){
      s16x8 pa = *(const s16x8*)(pw + ((l16*64 + jk*32 + quad*8) ^ ((l16&7)<<3)));
      lacc = MFMA(pa, ones, lacc);
      #pragma unroll
      for(int ds=0;ds<4;ds++){
        s16x8 vf = *(const s16x8*)(Vt + (ds*2+jk)*512 + lane*8);
        oacc[ds] = MFMA(pa, vf, oacc[ds]);
      }
    }
    __builtin_amdgcn_s_setprio(0);
  };

  // prologue: stage jt=0, load pos jt=0
  STAGE(0, 0);
  LOADPOS(0);
  __syncthreads();                       // drains stage(0) (+ pos loads)

  #pragma unroll 1
  for(int jt2=0; jt2<8; ++jt2){
    int jt = jt2*2;
    // even phase: compute from buf0, stage jt+1 into buf1
    STAGE(jt+1, 1);
    COMPUTE(&kv[0][0], &kv[0][4096], jt+1);
    __syncthreads();                     // stage(jt+1) drained (had full compute to land)
    // odd phase: compute from buf1, stage jt+2 into buf0
    if(jt2 < 7) STAGE(jt+2, 0);
    COMPUTE(&kv[1][0], &kv[1][4096], jt+2);
    __syncthreads();
  }

  // epilogue: wave owns its rows end-to-end; write bf16 attn output directly
  float rl[4];
  #pragma unroll
  for(int r=0;r<4;r++) rl[r] = __builtin_amdgcn_rcpf(lacc[r]);
  #pragma unroll
  for(int ds=0; ds<4; ds++)
    #pragma unroll
    for(int r=0;r<4;r++)
      out[((size_t)(b*1024 + iw + quad*4 + r))*512 + h*64 + ds*16 + l16] =
          f2b(oacc[ds][r] * rl[r]);
}

// ---- out projection: fp32 out = a_bf @ Wo^T + bo + x, 64x64 tiles ----
__global__ __launch_bounds__(256) void gemm_out(
    const short* __restrict__ A, const short* __restrict__ B,
    const float* __restrict__ bias, const float* __restrict__ resid,
    float* __restrict__ Cout)
{
  __shared__ __align__(16) short At[64*32];
  __shared__ __align__(16) short Bt[64*32];
  int tid = threadIdx.x;
  int wave = tid >> 6, lane = tid & 63;
  int quad = lane >> 4, l16 = lane & 15;
  int wm = wave >> 1, wn = wave & 1;
  int m0 = blockIdx.y*64, n0 = blockIdx.x*64;
  int srow = lane >> 2, scol = (lane & 3)*8;
  f32x4 acc[2][2] = {};
  for(int k0=0; k0<512; k0+=32){
    int rb = wave*16;
    gload_lds16(A + (size_t)(m0 + rb + srow)*512 + k0 + scol, At + rb*32);
    gload_lds16(B + (size_t)(n0 + rb + srow)*512 + k0 + scol, Bt + rb*32);
    __syncthreads();
    s16x8 af[2], bfr[2];
    #pragma unroll
    for(int i=0;i<2;i++) af[i]  = *(const s16x8*)(At + (wm*32 + i*16 + l16)*32 + quad*8);
    #pragma unroll
    for(int j=0;j<2;j++) bfr[j] = *(const s16x8*)(Bt + (wn*32 + j*16 + l16)*32 + quad*8);
    #pragma unroll
    for(int i=0;i<2;i++)
      #pragma unroll
      for(int j=0;j<2;j++)
        acc[i][j] = MFMA(af[i], bfr[j], acc[i][j]);
    __syncthreads();
  }
  #pragma unroll
  for(int i=0;i<2;i++){
    int rowb = m0 + wm*32 + i*16 + quad*4;
    #pragma unroll
    for(int j=0;j<2;j++){
      int col = n0 + wn*32 + j*16 + l16;
      float bv = bias[col];
      #pragma unroll
      for(int r=0;r<4;r++){
        size_t idx = (size_t)(rowb + r)*512 + col;
        Cout[idx] = acc[i][j][r] + bv + resid[idx];
      }
    }
  }
}

extern "C" void kernel_launch(void* const* d_in, const int* in_sizes, int n_in,
                              void* d_out, int out_size, void* d_ws, size_t ws_size,
                              hipStream_t stream)
{
  const float* x    = (const float*)d_in[0];
  const float* pos  = (const float*)d_in[1];
  const float* lnw  = (const float*)d_in[2];
  const float* lnb  = (const float*)d_in[3];
  const float* Wq   = (const float*)d_in[4];
  const float* bq   = (const float*)d_in[5];
  const float* Wk   = (const float*)d_in[6];
  const float* bk   = (const float*)d_in[7];
  const float* Wv   = (const float*)d_in[8];
  const float* bv   = (const float*)d_in[9];
  const float* Wo   = (const float*)d_in[10];
  const float* bo   = (const float*)d_in[11];
  const float* Wp   = (const float*)d_in[12];
  const float* pbu  = (const float*)d_in[13];
  const float* pbv  = (const float*)d_in[14];
  float* out = (float*)d_out;

  char* ws = (char*)d_ws;
  short* h_bf    = (short*)(ws);                 // 8192x512
  short* q_sw    = (short*)(ws + ( 8u<<20));     // fragment-major
  short* k_sw    = (short*)(ws + (16u<<20));
  short* v_sw    = (short*)(ws + (24u<<20));
  short* a_bf    = (short*)(ws + (32u<<20));     // attn out, row-major
  short* p_sw    = (short*)(ws + (40u<<20));     // 2 MB
  short* pos_bf  = (short*)(ws + (42u<<20));     // 2 MB
  short* wqkv_bf = (short*)(ws + (44u<<20));     // 3 MB
  short* wo_bf   = (short*)(ws + (47u<<20));     // 0.5 MB
  short* wp_bf   = (short*)(ws + (47u<<20) + (512u<<10));

  prep_kernel<<<dim3(3200), 256, 0, stream>>>(Wq, Wk, Wv, Wo, Wp, pos,
                                              x, lnw, lnb,
                                              wqkv_bf, wo_bf, wp_bf, pos_bf, h_bf);
  gemm_fused<<<dim3(1024), 256, 0, stream>>>(h_bf, wqkv_bf, bq, bk, bv,
                                             pos_bf, wp_bf,
                                             q_sw, k_sw, v_sw, p_sw);
  attn_kernel<<<dim3(1024), 256, 0, stream>>>(q_sw, k_sw, v_sw, p_sw, pbu, pbv, a_bf);
  gemm_out<<<dim3(8,128), 256, 0, stream>>>(a_bf, wo_bf, bo, x, out);
  (void)in_sizes; (void)n_in; (void)out_size; (void)ws_size;
}

// Round 5
// 194.007 us; speedup vs baseline: 1.1210x; 1.1210x over previous
//
#include <hip/hip_runtime.h>
#include <hip/hip_bf16.h>

// ConformerAttention on MI355X (gfx950), bf16 MFMA internal, fp32 in/out.
// rel_shift(ps)[i,j] == ps[i, j-i+S-1]  -> banded pos-score, never materialize [S,P].
// R12: attn — exact R9 skeleton (natural grid order, 1 barrier/jt, K+V dbuf LDS,
//      stride-72 pw; no XCD remap) with 32 q-rows per wave (2 subtiles,
//      6-block pos band union shared, K/V fragments reused by both subtiles).
//      Halves block count -> halves staging traffic + barrier drains per work.

typedef __attribute__((ext_vector_type(8))) short  s16x8;
typedef __attribute__((ext_vector_type(8))) __bf16 bfv8;
typedef __attribute__((ext_vector_type(4))) float  f32x4;
typedef __attribute__((ext_vector_type(4))) unsigned u32x4;

__device__ __forceinline__ float b2f(short s){
  unsigned u = ((unsigned)(unsigned short)s) << 16;
  float f; __builtin_memcpy(&f, &u, 4); return f;
}
__device__ __forceinline__ short f2b(float f){
  unsigned u; __builtin_memcpy(&u, &f, 4);
  u = (u + 0x7fffu + ((u >> 16) & 1u)) >> 16;
  return (short)u;
}
// packed 2xf32 -> 2xbf16 (v_cvt_pk_bf16_f32 on gfx950), low = first arg
__device__ __forceinline__ unsigned pk2(float lo, float hi){
  __hip_bfloat162 t = __float22bfloat162_rn(make_float2(lo, hi));
  unsigned u; __builtin_memcpy(&u, &t, 4); return u;
}
__device__ __forceinline__ f32x4 MFMA(s16x8 a, s16x8 b, f32x4 c){
  return __builtin_amdgcn_mfma_f32_16x16x32_bf16(
      __builtin_bit_cast(bfv8, a), __builtin_bit_cast(bfv8, b), c, 0, 0, 0);
}
__device__ __forceinline__ void gload_lds16(const void* g, void* l){
  __builtin_amdgcn_global_load_lds(
      (const __attribute__((address_space(1))) void*)g,
      (__attribute__((address_space(3))) void*)l, 16, 0, 0);
}
__device__ __forceinline__ void cvt8(const float* in, short* out, size_t i8){
  f32x4 a = *(const f32x4*)(in + i8*8);
  f32x4 b = *(const f32x4*)(in + i8*8 + 4);
  u32x4 o;
  o[0] = pk2(a[0],a[1]); o[1] = pk2(a[2],a[3]);
  o[2] = pk2(b[0],b[1]); o[3] = pk2(b[2],b[3]);
  *(u32x4*)(out + i8*8) = o;
}

// ---- prep: weight/pos converts + LayerNorm, one launch ----
__global__ __launch_bounds__(256) void prep_kernel(
    const float* __restrict__ Wq, const float* __restrict__ Wk,
    const float* __restrict__ Wv, const float* __restrict__ Wo,
    const float* __restrict__ Wp, const float* __restrict__ pos,
    const float* __restrict__ x, const float* __restrict__ lnw, const float* __restrict__ lnb,
    short* __restrict__ wqkv, short* __restrict__ wo, short* __restrict__ wp,
    short* __restrict__ posbf, short* __restrict__ h_bf)
{
  int bid = blockIdx.x, tid = threadIdx.x;
  if(bid < 640){
    int w = bid >> 7;
    size_t i = (size_t)(bid & 127)*256 + tid;
    const float* src; short* dst;
    if(w == 0){ src = Wq; dst = wqkv; }
    else if(w == 1){ src = Wk; dst = wqkv + 262144; }
    else if(w == 2){ src = Wv; dst = wqkv + 524288; }
    else if(w == 3){ src = Wo; dst = wo; }
    else { src = Wp; dst = wp; }
    cvt8(src, dst, i);
  } else if(bid < 1152){
    size_t i = (size_t)(bid - 640)*256 + tid;
    if(i < 131008) cvt8(pos, posbf, i);        // 2047*512/8
  } else {
    int row = (bid - 1152)*4 + (tid >> 6);
    int lane = tid & 63;
    const float* xr = x + (size_t)row*512;
    f32x4 v0 = *(const f32x4*)(xr + lane*8);
    f32x4 v1 = *(const f32x4*)(xr + lane*8 + 4);
    float s  = v0[0]+v0[1]+v0[2]+v0[3]+v1[0]+v1[1]+v1[2]+v1[3];
    float s2 = v0[0]*v0[0]+v0[1]*v0[1]+v0[2]*v0[2]+v0[3]*v0[3]
             + v1[0]*v1[0]+v1[1]*v1[1]+v1[2]*v1[2]+v1[3]*v1[3];
    #pragma unroll
    for(int m=1;m<64;m<<=1){ s += __shfl_xor(s,m); s2 += __shfl_xor(s2,m); }
    float mu = s * (1.0f/512.0f);
    float rs = rsqrtf(s2*(1.0f/512.0f) - mu*mu + 1e-5f);
    float y[8];
    #pragma unroll
    for(int e=0;e<8;e++){
      float xv = (e<4)? v0[e] : v1[e-4];
      int d = lane*8 + e;
      y[e] = (xv - mu)*rs*lnw[d] + lnb[d];
    }
    u32x4 o;
    o[0]=pk2(y[0],y[1]); o[1]=pk2(y[2],y[3]); o[2]=pk2(y[4],y[5]); o[3]=pk2(y[6],y[7]);
    *(u32x4*)(h_bf + (size_t)row*512 + lane*8) = o;
  }
}

// ---- fused QKV GEMM (768 blocks, 128x128) + pos GEMM (256 blocks, 64x64) ----
__global__ __launch_bounds__(256) void gemm_fused(
    const short* __restrict__ h_bf, const short* __restrict__ wqkv,
    const float* __restrict__ bq, const float* __restrict__ bk, const float* __restrict__ bv,
    const short* __restrict__ posbf, const short* __restrict__ wp,
    short* __restrict__ q_sw, short* __restrict__ k_sw, short* __restrict__ v_sw,
    short* __restrict__ p_sw)
{
  __shared__ __align__(16) short smem[9216];   // At|Bt staging, then C-tile staging
  short* At = smem;
  short* Bt = smem + 4096;
  int bid = blockIdx.x, tid = threadIdx.x;
  int wave = tid >> 6, lane = tid & 63;
  int quad = lane >> 4, l16 = lane & 15;
  int srow = lane >> 2, scol = (lane & 3)*8;
  if(bid < 768){
    int bx = bid % 12, by = bid / 12;
    int m0 = by*128, n0 = bx*128;
    int wm = wave >> 1, wn = wave & 1;
    f32x4 acc[4][4] = {};
    for(int k0=0; k0<512; k0+=32){
      #pragma unroll
      for(int c=0;c<2;c++){
        int rb = (wave + 4*c)*16;
        gload_lds16(h_bf + (size_t)(m0 + rb + srow)*512 + k0 + scol, At + rb*32);
        gload_lds16(wqkv + (size_t)(n0 + rb + srow)*512 + k0 + scol, Bt + rb*32);
      }
      __syncthreads();
      s16x8 af[4], bfr[4];
      #pragma unroll
      for(int i=0;i<4;i++) af[i]  = *(const s16x8*)(At + (wm*64 + i*16 + l16)*32 + quad*8);
      #pragma unroll
      for(int j=0;j<4;j++) bfr[j] = *(const s16x8*)(Bt + (wn*64 + j*16 + l16)*32 + quad*8);
      #pragma unroll
      for(int i=0;i<4;i++)
        #pragma unroll
        for(int j=0;j<4;j++)
          acc[i][j] = MFMA(af[i], bfr[j], acc[i][j]);
      __syncthreads();
    }
    int seg = bx >> 2;               // 0 q, 1 k, 2 v (uniform per block)
    int nseg = (bx & 3)*128;
    int bb = by >> 3;
    const float* bsrc = (seg==0)? bq : (seg==1)? bk : bv;
    float bias_j[4];
    #pragma unroll
    for(int j=0;j<4;j++) bias_j[j] = bsrc[nseg + wn*64 + j*16 + l16];
    if(seg < 2){
      short* dst = seg ? k_sw : q_sw;
      #pragma unroll
      for(int h2=0; h2<2; h2++){
        if(wm == h2){
          #pragma unroll
          for(int i=0;i<4;i++){
            int lr = i*16 + quad*4;
            #pragma unroll
            for(int j=0;j<4;j++){
              int cl = wn*64 + j*16 + l16;
              unsigned p01 = pk2(acc[i][j][0]+bias_j[j], acc[i][j][1]+bias_j[j]);
              unsigned p23 = pk2(acc[i][j][2]+bias_j[j], acc[i][j][3]+bias_j[j]);
              smem[(lr+0)*136 + cl] = (short)p01;
              smem[(lr+1)*136 + cl] = (short)(p01>>16);
              smem[(lr+2)*136 + cl] = (short)p23;
              smem[(lr+3)*136 + cl] = (short)(p23>>16);
            }
          }
        }
        __syncthreads();
        #pragma unroll
        for(int it=0; it<4; it++){
          int ci = it*4 + wave;              // hs = ci>>2 (head/ks slot), tb = ci&3
          int hs = ci >> 2, tb = ci & 3;
          s16x8 vv = *(const s16x8*)(smem + (tb*16 + l16)*136 + hs*32 + quad*8);
          int hh = (nseg>>6) + (hs>>1);
          int tg = ((m0 + h2*64)>>4) + tb;
          size_t chunk = ((size_t)((bb*8 + hh)*64 + tg))*2 + (hs&1);
          *(s16x8*)(dst + chunk*512 + (size_t)lane*8) = vv;
        }
        __syncthreads();
      }
    } else {
      // V: stage transposed Ct_v[dim 0..127][token 0..63], stride 72
      #pragma unroll
      for(int h2=0; h2<2; h2++){
        int jt = by*2 + h2;
        if(wm == h2){
          #pragma unroll
          for(int i=0;i<4;i++){
            int tl = i*16 + quad*4;
            #pragma unroll
            for(int j=0;j<4;j++){
              int dl = wn*64 + j*16 + l16;
              unsigned p01 = pk2(acc[i][j][0]+bias_j[j], acc[i][j][1]+bias_j[j]);
              unsigned p23 = pk2(acc[i][j][2]+bias_j[j], acc[i][j][3]+bias_j[j]);
              unsigned* w2 = (unsigned*)(smem + dl*72 + tl);
              w2[0] = p01; w2[1] = p23;
            }
          }
        }
        __syncthreads();
        #pragma unroll
        for(int it=0; it<4; it++){
          int ci = it*4 + wave;              // ci = hl*8 + ds*2 + jk
          int hl = ci>>3, ds = (ci>>1)&3, jk = ci&1;
          s16x8 vv = *(const s16x8*)(smem + (hl*64 + ds*16 + l16)*72 + jk*32 + quad*8);
          int hh = (nseg>>6) + hl;
          size_t chunk = (((size_t)((bb*8 + hh)*16 + jt))*4 + ds)*2 + jk;
          *(s16x8*)(v_sw + chunk*512 + (size_t)lane*8) = vv;
        }
        __syncthreads();
      }
    }
  } else {
    // pos projection: [2048,512] = posbf(2047 rows, clamped) @ wp^T, 64x64 tiles
    int pid = bid - 768;
    int bx = pid % 8, by = pid / 8;
    int m0 = by*64, n0 = bx*64;
    int wm = wave >> 1, wn = wave & 1;
    f32x4 acc[2][2] = {};
    for(int k0=0; k0<512; k0+=32){
      int rb = wave*16;
      int ra = m0 + rb + srow; if(ra > 2046) ra = 2046;
      gload_lds16(posbf + (size_t)ra*512 + k0 + scol, At + rb*32);
      gload_lds16(wp + (size_t)(n0 + rb + srow)*512 + k0 + scol, Bt + rb*32);
      __syncthreads();
      s16x8 af[2], bfr[2];
      #pragma unroll
      for(int i=0;i<2;i++) af[i]  = *(const s16x8*)(At + (wm*32 + i*16 + l16)*32 + quad*8);
      #pragma unroll
      for(int j=0;j<2;j++) bfr[j] = *(const s16x8*)(Bt + (wn*32 + j*16 + l16)*32 + quad*8);
      #pragma unroll
      for(int i=0;i<2;i++)
        #pragma unroll
        for(int j=0;j<2;j++)
          acc[i][j] = MFMA(af[i], bfr[j], acc[i][j]);
      __syncthreads();
    }
    #pragma unroll
    for(int i=0;i<2;i++){
      int rowb = m0 + wm*32 + i*16 + quad*4;          // rowb&15 = quad*4
      #pragma unroll
      for(int j=0;j<2;j++){
        int col = n0 + wn*32 + j*16 + l16;
        int hh = col>>6, ks = (col>>5)&1, qd = (col>>3)&3, e = col&7;
        int rblk = rowb>>4;
        size_t base = ((size_t)(((hh*128+rblk)*2+ks)*64) + qd*16)*8 + e;
        #pragma unroll
        for(int r=0;r<4;r++)
          p_sw[base + (size_t)(quad*4+r)*8] = f2b(acc[i][j][r]);
      }
    }
  }
}

// ---- Fused rel-pos attention (R12): grid (8,8,8) natural order; 4 waves; wave
// w owns 32 q-rows [qt*128 + w*32, +32) as 2 subtiles and iterates all 16 key
// tiles. K+V tiles double-buffered in LDS via global_load_lds, ONE barrier per
// jt (R9 schedule). Pos fragments register-prefetched one jt ahead over the
// 6-block band union shared by both subtiles; K/V fragments reused by both
// subtiles. Linear (no-max) softmax (exact 0.125 fold, __expf); rotated
// pos-score fed as QK MFMA C-init; denominator via ones-splat PV MFMA.
__global__ __launch_bounds__(256, 2) void attn_kernel(
    const short* __restrict__ q_sw, const short* __restrict__ k_sw,
    const short* __restrict__ v_sw, const short* __restrict__ p_sw,
    const float* __restrict__ bu, const float* __restrict__ bvv,
    short* __restrict__ out)
{
  __shared__ __align__(16) short kv[2][8192];   // [buf][units 0..7 = K | 8..15 = V]
  __shared__ __align__(16) short pwall[9216];   // 4 waves x 2 subtiles x 16x72
  int tid = threadIdx.x;
  int wave = tid >> 6, lane = tid & 63, quad = lane >> 4, l16 = lane & 15;
  int h = blockIdx.y, b = blockIdx.z, bh = b*8 + h;
  int qt = blockIdx.x;               // 128-row q block
  int iblk32 = qt*4 + wave;          // this wave's 32-row unit (0..31)
  int iw = iblk32*32;
  short* pw = pwall + wave*2304;     // two 16x72 bf16 P tiles

  const short* qb = q_sw + (size_t)bh*65536;
  const short* kb = k_sw + (size_t)bh*65536;
  const short* vb = v_sw + (size_t)bh*65536;
  const short* pb = p_sw + (size_t)h*131072;

  // q fragments for both subtiles; bias + exact 0.125 scale folded
  s16x8 qu[2][2], qv[2][2];
  #pragma unroll
  for(int s=0;s<2;s++){
    #pragma unroll
    for(int ks=0;ks<2;ks++){
      s16x8 qr = *(const s16x8*)(qb + ((size_t)((iblk32*2+s)*2+ks)*64 + lane)*8);
      short tu[8], tv[8];
      #pragma unroll
      for(int e=0;e<8;e++){
        int d = h*64 + ks*32 + quad*8 + e;
        float f = b2f(qr[e]);
        tu[e] = f2b((f + bu[d]) * 0.125f);
        tv[e] = f2b((f + bvv[d]) * 0.125f);
      }
      qu[s][ks] = *(s16x8*)tu; qv[s][ks] = *(s16x8*)tv;
    }
  }

  // ones splat for the denominator MFMA (bf16 1.0 = 0x3F80)
  s16x8 ones;
  #pragma unroll
  for(int e=0;e<8;e++) ones[e] = (short)0x3F80;

  // hoisted band-gather controls (per accumulator register r; row-in-subtile)
  int srcl[4]; bool lo[4];
  #pragma unroll
  for(int r=0;r<4;r++){
    int il = quad*4 + r;
    srcl[r] = quad*16 + ((l16 + 15 - il) & 15);
    lo[r]   = (l16 <= il);
  }

  f32x4 oacc[2][4] = {};
  f32x4 lacc[2] = {};
  s16x8 Pa[6][2];                    // prefetched pos fragments, 6-block union

  // cooperative K/V stage: unit = wave*4 + r; units 0..7 = K tile, 8..15 = V tile.
  auto STAGE = [&](int jt, int bufi){
    const short* base = (wave < 2) ? kb : vb;
    #pragma unroll
    for(int r=0;r<4;r++){
      int unit = wave*4 + r;
      gload_lds16(base + (size_t)jt*4096 + (unit&7)*512 + lane*8,
                  &kv[bufi][unit*512]);
    }
  };
  // band union for this wave's 32 rows: subtile0 window rb0..rb0+4,
  // subtile1 window rb0-1..rb0+3; union rb0-1..rb0+4 (6 blocks).
  auto LOADPOS = [&](int jt){
    int rb0 = (jt*64 - iw + 1008) >> 4;
    #pragma unroll
    for(int nt=0;nt<6;nt++)
      #pragma unroll
      for(int ks=0;ks<2;ks++)
        Pa[nt][ks] = *(const s16x8*)(pb + (size_t)((rb0-1+nt)*2+ks)*512 + lane*8);
  };
  auto COMPUTE = [&](const short* Kt, const short* Vt, int next_jt){
    // pos MFMAs consume Pa over the union; then Pa refilled for next_jt.
    f32x4 ps0[5], ps1[5];
    __builtin_amdgcn_s_setprio(1);
    #pragma unroll
    for(int nt=0;nt<6;nt++){
      s16x8 pf0 = Pa[nt][0], pf1 = Pa[nt][1];
      if(nt >= 1){
        f32x4 a = {};
        a = MFMA(qv[0][0], pf0, a);
        a = MFMA(qv[0][1], pf1, a);
        ps0[nt-1] = a;
      }
      if(nt <= 4){
        f32x4 a = {};
        a = MFMA(qv[1][0], pf0, a);
        a = MFMA(qv[1][1], pf1, a);
        ps1[nt] = a;
      }
    }
    __builtin_amdgcn_s_setprio(0);
    if(next_jt < 16) LOADPOS(next_jt);
    // rotate band lanes (both subtiles)
    float rot0[4][5], rot1[4][5];
    #pragma unroll
    for(int r=0;r<4;r++){
      #pragma unroll
      for(int nt=0;nt<5;nt++){
        rot0[r][nt] = __shfl(ps0[nt][r], srcl[r]);
        rot1[r][nt] = __shfl(ps1[nt][r], srcl[r]);
      }
    }
    // content scores with rotated pos-score as C-init; exp; P->LDS.
    // K fragments loaded once per js, used by both subtiles.
    #pragma unroll
    for(int js=0;js<4;js++){
      s16x8 kf0 = *(const s16x8*)(Kt + (js*2+0)*512 + lane*8);
      s16x8 kf1 = *(const s16x8*)(Kt + (js*2+1)*512 + lane*8);
      int col = js*16 + l16;
      {
        f32x4 c0;
        #pragma unroll
        for(int r=0;r<4;r++) c0[r] = lo[r] ? rot0[r][js] : rot0[r][js+1];
        f32x4 a = MFMA(qu[0][0], kf0, c0);
        a = MFMA(qu[0][1], kf1, a);
        unsigned p01 = pk2(__expf(a[0]), __expf(a[1]));
        unsigned p23 = pk2(__expf(a[2]), __expf(a[3]));
        pw[(quad*4+0)*72 + col] = (short)p01;
        pw[(quad*4+1)*72 + col] = (short)(p01>>16);
        pw[(quad*4+2)*72 + col] = (short)p23;
        pw[(quad*4+3)*72 + col] = (short)(p23>>16);
      }
      {
        f32x4 c0;
        #pragma unroll
        for(int r=0;r<4;r++) c0[r] = lo[r] ? rot1[r][js] : rot1[r][js+1];
        f32x4 a = MFMA(qu[1][0], kf0, c0);
        a = MFMA(qu[1][1], kf1, a);
        unsigned p01 = pk2(__expf(a[0]), __expf(a[1]));
        unsigned p23 = pk2(__expf(a[2]), __expf(a[3]));
        pw[1152 + (quad*4+0)*72 + col] = (short)p01;
        pw[1152 + (quad*4+1)*72 + col] = (short)(p01>>16);
        pw[1152 + (quad*4+2)*72 + col] = (short)p23;
        pw[1152 + (quad*4+3)*72 + col] = (short)(p23>>16);
      }
    }
    // PV: 2 j-ksteps x (4 d-subtiles + ones row-sum); V fragments shared.
    __builtin_amdgcn_s_setprio(1);
    #pragma unroll
    for(int jk=0;jk<2;jk++){
      s16x8 pa0 = *(const s16x8*)(pw + l16*72 + jk*32 + quad*8);
      s16x8 pa1 = *(const s16x8*)(pw + 1152 + l16*72 + jk*32 + quad*8);
      lacc[0] = MFMA(pa0, ones, lacc[0]);
      lacc[1] = MFMA(pa1, ones, lacc[1]);
      #pragma unroll
      for(int ds=0;ds<4;ds++){
        s16x8 vf = *(const s16x8*)(Vt + (ds*2+jk)*512 + lane*8);
        oacc[0][ds] = MFMA(pa0, vf, oacc[0][ds]);
        oacc[1][ds] = MFMA(pa1, vf, oacc[1][ds]);
      }
    }
    __builtin_amdgcn_s_setprio(0);
  };

  // prologue: stage jt=0, load pos jt=0
  STAGE(0, 0);
  LOADPOS(0);
  __syncthreads();                       // drains stage(0) (+ pos loads)

  #pragma unroll 1
  for(int jt2=0; jt2<8; ++jt2){
    int jt = jt2*2;
    // even phase: compute from buf0, stage jt+1 into buf1
    STAGE(jt+1, 1);
    COMPUTE(&kv[0][0], &kv[0][4096], jt+1);
    __syncthreads();                     // stage(jt+1) drained (had full compute to land)
    // odd phase: compute from buf1, stage jt+2 into buf0
    if(jt2 < 7) STAGE(jt+2, 0);
    COMPUTE(&kv[1][0], &kv[1][4096], jt+2);
    __syncthreads();
  }

  // epilogue: wave owns its rows end-to-end; write bf16 attn output directly
  #pragma unroll
  for(int s=0;s<2;s++){
    float rl[4];
    #pragma unroll
    for(int r=0;r<4;r++) rl[r] = __builtin_amdgcn_rcpf(lacc[s][r]);
    #pragma unroll
    for(int ds=0; ds<4; ds++)
      #pragma unroll
      for(int r=0;r<4;r++)
        out[((size_t)(b*1024 + iw + s*16 + quad*4 + r))*512 + h*64 + ds*16 + l16] =
            f2b(oacc[s][ds][r] * rl[r]);
  }
}

// ---- out projection: fp32 out = a_bf @ Wo^T + bo + x, 64x64 tiles ----
__global__ __launch_bounds__(256) void gemm_out(
    const short* __restrict__ A, const short* __restrict__ B,
    const float* __restrict__ bias, const float* __restrict__ resid,
    float* __restrict__ Cout)
{
  __shared__ __align__(16) short At[64*32];
  __shared__ __align__(16) short Bt[64*32];
  int tid = threadIdx.x;
  int wave = tid >> 6, lane = tid & 63;
  int quad = lane >> 4, l16 = lane & 15;
  int wm = wave >> 1, wn = wave & 1;
  int m0 = blockIdx.y*64, n0 = blockIdx.x*64;
  int srow = lane >> 2, scol = (lane & 3)*8;
  f32x4 acc[2][2] = {};
  for(int k0=0; k0<512; k0+=32){
    int rb = wave*16;
    gload_lds16(A + (size_t)(m0 + rb + srow)*512 + k0 + scol, At + rb*32);
    gload_lds16(B + (size_t)(n0 + rb + srow)*512 + k0 + scol, Bt + rb*32);
    __syncthreads();
    s16x8 af[2], bfr[2];
    #pragma unroll
    for(int i=0;i<2;i++) af[i]  = *(const s16x8*)(At + (wm*32 + i*16 + l16)*32 + quad*8);
    #pragma unroll
    for(int j=0;j<2;j++) bfr[j] = *(const s16x8*)(Bt + (wn*32 + j*16 + l16)*32 + quad*8);
    #pragma unroll
    for(int i=0;i<2;i++)
      #pragma unroll
      for(int j=0;j<2;j++)
        acc[i][j] = MFMA(af[i], bfr[j], acc[i][j]);
    __syncthreads();
  }
  #pragma unroll
  for(int i=0;i<2;i++){
    int rowb = m0 + wm*32 + i*16 + quad*4;
    #pragma unroll
    for(int j=0;j<2;j++){
      int col = n0 + wn*32 + j*16 + l16;
      float bv = bias[col];
      #pragma unroll
      for(int r=0;r<4;r++){
        size_t idx = (size_t)(rowb + r)*512 + col;
        Cout[idx] = acc[i][j][r] + bv + resid[idx];
      }
    }
  }
}

extern "C" void kernel_launch(void* const* d_in, const int* in_sizes, int n_in,
                              void* d_out, int out_size, void* d_ws, size_t ws_size,
                              hipStream_t stream)
{
  const float* x    = (const float*)d_in[0];
  const float* pos  = (const float*)d_in[1];
  const float* lnw  = (const float*)d_in[2];
  const float* lnb  = (const float*)d_in[3];
  const float* Wq   = (const float*)d_in[4];
  const float* bq   = (const float*)d_in[5];
  const float* Wk   = (const float*)d_in[6];
  const float* bk   = (const float*)d_in[7];
  const float* Wv   = (const float*)d_in[8];
  const float* bv   = (const float*)d_in[9];
  const float* Wo   = (const float*)d_in[10];
  const float* bo   = (const float*)d_in[11];
  const float* Wp   = (const float*)d_in[12];
  const float* pbu  = (const float*)d_in[13];
  const float* pbv  = (const float*)d_in[14];
  float* out = (float*)d_out;

  char* ws = (char*)d_ws;
  short* h_bf    = (short*)(ws);                 // 8192x512
  short* q_sw    = (short*)(ws + ( 8u<<20));     // fragment-major
  short* k_sw    = (short*)(ws + (16u<<20));
  short* v_sw    = (short*)(ws + (24u<<20));
  short* a_bf    = (short*)(ws + (32u<<20));     // attn out, row-major
  short* p_sw    = (short*)(ws + (40u<<20));     // 2 MB
  short* pos_bf  = (short*)(ws + (42u<<20));     // 2 MB
  short* wqkv_bf = (short*)(ws + (44u<<20));     // 3 MB
  short* wo_bf   = (short*)(ws + (47u<<20));     // 0.5 MB
  short* wp_bf   = (short*)(ws + (47u<<20) + (512u<<10));

  prep_kernel<<<dim3(3200), 256, 0, stream>>>(Wq, Wk, Wv, Wo, Wp, pos,
                                              x, lnw, lnb,
                                              wqkv_bf, wo_bf, wp_bf, pos_bf, h_bf);
  gemm_fused<<<dim3(1024), 256, 0, stream>>>(h_bf, wqkv_bf, bq, bk, bv,
                                             pos_bf, wp_bf,
                                             q_sw, k_sw, v_sw, p_sw);
  attn_kernel<<<dim3(8,8,8), 256, 0, stream>>>(q_sw, k_sw, v_sw, p_sw, pbu, pbv, a_bf);
  gemm_out<<<dim3(8,128), 256, 0, stream>>>(a_bf, wo_bf, bo, x, out);
  (void)in_sizes; (void)n_in; (void)out_size; (void)ws_size;
}

// Round 6
// 192.762 us; speedup vs baseline: 1.1283x; 1.0065x over previous
//
#include <hip/hip_runtime.h>
#include <hip/hip_bf16.h>

// ConformerAttention on MI355X (gfx950), bf16 MFMA internal, fp32 in/out.
// rel_shift(ps)[i,j] == ps[i, j-i+S-1]  -> banded pos-score, never materialize [S,P].
// R13: attn — 8 waves x 32 rows (256 blocks, 1/CU, whole grid co-resident);
//      staging 2 gload/wave/jt; barrier events per work halved again; compact
//      XOR-swizzled pw (R11-proven conflict-free) keeps LDS at exactly 64 KB.
//      gemm_out — 128x128 tiles cloning gemm_fused's proven k-loop (4x MFMA
//      density, 1/4 the blocks/barriers).

typedef __attribute__((ext_vector_type(8))) short  s16x8;
typedef __attribute__((ext_vector_type(8))) __bf16 bfv8;
typedef __attribute__((ext_vector_type(4))) float  f32x4;
typedef __attribute__((ext_vector_type(4))) unsigned u32x4;

__device__ __forceinline__ float b2f(short s){
  unsigned u = ((unsigned)(unsigned short)s) << 16;
  float f; __builtin_memcpy(&f, &u, 4); return f;
}
__device__ __forceinline__ short f2b(float f){
  unsigned u; __builtin_memcpy(&u, &f, 4);
  u = (u + 0x7fffu + ((u >> 16) & 1u)) >> 16;
  return (short)u;
}
// packed 2xf32 -> 2xbf16 (v_cvt_pk_bf16_f32 on gfx950), low = first arg
__device__ __forceinline__ unsigned pk2(float lo, float hi){
  __hip_bfloat162 t = __float22bfloat162_rn(make_float2(lo, hi));
  unsigned u; __builtin_memcpy(&u, &t, 4); return u;
}
__device__ __forceinline__ f32x4 MFMA(s16x8 a, s16x8 b, f32x4 c){
  return __builtin_amdgcn_mfma_f32_16x16x32_bf16(
      __builtin_bit_cast(bfv8, a), __builtin_bit_cast(bfv8, b), c, 0, 0, 0);
}
__device__ __forceinline__ void gload_lds16(const void* g, void* l){
  __builtin_amdgcn_global_load_lds(
      (const __attribute__((address_space(1))) void*)g,
      (__attribute__((address_space(3))) void*)l, 16, 0, 0);
}
__device__ __forceinline__ void cvt8(const float* in, short* out, size_t i8){
  f32x4 a = *(const f32x4*)(in + i8*8);
  f32x4 b = *(const f32x4*)(in + i8*8 + 4);
  u32x4 o;
  o[0] = pk2(a[0],a[1]); o[1] = pk2(a[2],a[3]);
  o[2] = pk2(b[0],b[1]); o[3] = pk2(b[2],b[3]);
  *(u32x4*)(out + i8*8) = o;
}

// ---- prep: weight/pos converts + LayerNorm, one launch ----
__global__ __launch_bounds__(256) void prep_kernel(
    const float* __restrict__ Wq, const float* __restrict__ Wk,
    const float* __restrict__ Wv, const float* __restrict__ Wo,
    const float* __restrict__ Wp, const float* __restrict__ pos,
    const float* __restrict__ x, const float* __restrict__ lnw, const float* __restrict__ lnb,
    short* __restrict__ wqkv, short* __restrict__ wo, short* __restrict__ wp,
    short* __restrict__ posbf, short* __restrict__ h_bf)
{
  int bid = blockIdx.x, tid = threadIdx.x;
  if(bid < 640){
    int w = bid >> 7;
    size_t i = (size_t)(bid & 127)*256 + tid;
    const float* src; short* dst;
    if(w == 0){ src = Wq; dst = wqkv; }
    else if(w == 1){ src = Wk; dst = wqkv + 262144; }
    else if(w == 2){ src = Wv; dst = wqkv + 524288; }
    else if(w == 3){ src = Wo; dst = wo; }
    else { src = Wp; dst = wp; }
    cvt8(src, dst, i);
  } else if(bid < 1152){
    size_t i = (size_t)(bid - 640)*256 + tid;
    if(i < 131008) cvt8(pos, posbf, i);        // 2047*512/8
  } else {
    int row = (bid - 1152)*4 + (tid >> 6);
    int lane = tid & 63;
    const float* xr = x + (size_t)row*512;
    f32x4 v0 = *(const f32x4*)(xr + lane*8);
    f32x4 v1 = *(const f32x4*)(xr + lane*8 + 4);
    float s  = v0[0]+v0[1]+v0[2]+v0[3]+v1[0]+v1[1]+v1[2]+v1[3];
    float s2 = v0[0]*v0[0]+v0[1]*v0[1]+v0[2]*v0[2]+v0[3]*v0[3]
             + v1[0]*v1[0]+v1[1]*v1[1]+v1[2]*v1[2]+v1[3]*v1[3];
    #pragma unroll
    for(int m=1;m<64;m<<=1){ s += __shfl_xor(s,m); s2 += __shfl_xor(s2,m); }
    float mu = s * (1.0f/512.0f);
    float rs = rsqrtf(s2*(1.0f/512.0f) - mu*mu + 1e-5f);
    float y[8];
    #pragma unroll
    for(int e=0;e<8;e++){
      float xv = (e<4)? v0[e] : v1[e-4];
      int d = lane*8 + e;
      y[e] = (xv - mu)*rs*lnw[d] + lnb[d];
    }
    u32x4 o;
    o[0]=pk2(y[0],y[1]); o[1]=pk2(y[2],y[3]); o[2]=pk2(y[4],y[5]); o[3]=pk2(y[6],y[7]);
    *(u32x4*)(h_bf + (size_t)row*512 + lane*8) = o;
  }
}

// ---- fused QKV GEMM (768 blocks, 128x128) + pos GEMM (256 blocks, 64x64) ----
__global__ __launch_bounds__(256) void gemm_fused(
    const short* __restrict__ h_bf, const short* __restrict__ wqkv,
    const float* __restrict__ bq, const float* __restrict__ bk, const float* __restrict__ bv,
    const short* __restrict__ posbf, const short* __restrict__ wp,
    short* __restrict__ q_sw, short* __restrict__ k_sw, short* __restrict__ v_sw,
    short* __restrict__ p_sw)
{
  __shared__ __align__(16) short smem[9216];   // At|Bt staging, then C-tile staging
  short* At = smem;
  short* Bt = smem + 4096;
  int bid = blockIdx.x, tid = threadIdx.x;
  int wave = tid >> 6, lane = tid & 63;
  int quad = lane >> 4, l16 = lane & 15;
  int srow = lane >> 2, scol = (lane & 3)*8;
  if(bid < 768){
    int bx = bid % 12, by = bid / 12;
    int m0 = by*128, n0 = bx*128;
    int wm = wave >> 1, wn = wave & 1;
    f32x4 acc[4][4] = {};
    for(int k0=0; k0<512; k0+=32){
      #pragma unroll
      for(int c=0;c<2;c++){
        int rb = (wave + 4*c)*16;
        gload_lds16(h_bf + (size_t)(m0 + rb + srow)*512 + k0 + scol, At + rb*32);
        gload_lds16(wqkv + (size_t)(n0 + rb + srow)*512 + k0 + scol, Bt + rb*32);
      }
      __syncthreads();
      s16x8 af[4], bfr[4];
      #pragma unroll
      for(int i=0;i<4;i++) af[i]  = *(const s16x8*)(At + (wm*64 + i*16 + l16)*32 + quad*8);
      #pragma unroll
      for(int j=0;j<4;j++) bfr[j] = *(const s16x8*)(Bt + (wn*64 + j*16 + l16)*32 + quad*8);
      #pragma unroll
      for(int i=0;i<4;i++)
        #pragma unroll
        for(int j=0;j<4;j++)
          acc[i][j] = MFMA(af[i], bfr[j], acc[i][j]);
      __syncthreads();
    }
    int seg = bx >> 2;               // 0 q, 1 k, 2 v (uniform per block)
    int nseg = (bx & 3)*128;
    int bb = by >> 3;
    const float* bsrc = (seg==0)? bq : (seg==1)? bk : bv;
    float bias_j[4];
    #pragma unroll
    for(int j=0;j<4;j++) bias_j[j] = bsrc[nseg + wn*64 + j*16 + l16];
    if(seg < 2){
      short* dst = seg ? k_sw : q_sw;
      #pragma unroll
      for(int h2=0; h2<2; h2++){
        if(wm == h2){
          #pragma unroll
          for(int i=0;i<4;i++){
            int lr = i*16 + quad*4;
            #pragma unroll
            for(int j=0;j<4;j++){
              int cl = wn*64 + j*16 + l16;
              unsigned p01 = pk2(acc[i][j][0]+bias_j[j], acc[i][j][1]+bias_j[j]);
              unsigned p23 = pk2(acc[i][j][2]+bias_j[j], acc[i][j][3]+bias_j[j]);
              smem[(lr+0)*136 + cl] = (short)p01;
              smem[(lr+1)*136 + cl] = (short)(p01>>16);
              smem[(lr+2)*136 + cl] = (short)p23;
              smem[(lr+3)*136 + cl] = (short)(p23>>16);
            }
          }
        }
        __syncthreads();
        #pragma unroll
        for(int it=0; it<4; it++){
          int ci = it*4 + wave;              // hs = ci>>2 (head/ks slot), tb = ci&3
          int hs = ci >> 2, tb = ci & 3;
          s16x8 vv = *(const s16x8*)(smem + (tb*16 + l16)*136 + hs*32 + quad*8);
          int hh = (nseg>>6) + (hs>>1);
          int tg = ((m0 + h2*64)>>4) + tb;
          size_t chunk = ((size_t)((bb*8 + hh)*64 + tg))*2 + (hs&1);
          *(s16x8*)(dst + chunk*512 + (size_t)lane*8) = vv;
        }
        __syncthreads();
      }
    } else {
      // V: stage transposed Ct_v[dim 0..127][token 0..63], stride 72
      #pragma unroll
      for(int h2=0; h2<2; h2++){
        int jt = by*2 + h2;
        if(wm == h2){
          #pragma unroll
          for(int i=0;i<4;i++){
            int tl = i*16 + quad*4;
            #pragma unroll
            for(int j=0;j<4;j++){
              int dl = wn*64 + j*16 + l16;
              unsigned p01 = pk2(acc[i][j][0]+bias_j[j], acc[i][j][1]+bias_j[j]);
              unsigned p23 = pk2(acc[i][j][2]+bias_j[j], acc[i][j][3]+bias_j[j]);
              unsigned* w2 = (unsigned*)(smem + dl*72 + tl);
              w2[0] = p01; w2[1] = p23;
            }
          }
        }
        __syncthreads();
        #pragma unroll
        for(int it=0; it<4; it++){
          int ci = it*4 + wave;              // ci = hl*8 + ds*2 + jk
          int hl = ci>>3, ds = (ci>>1)&3, jk = ci&1;
          s16x8 vv = *(const s16x8*)(smem + (hl*64 + ds*16 + l16)*72 + jk*32 + quad*8);
          int hh = (nseg>>6) + hl;
          size_t chunk = (((size_t)((bb*8 + hh)*16 + jt))*4 + ds)*2 + jk;
          *(s16x8*)(v_sw + chunk*512 + (size_t)lane*8) = vv;
        }
        __syncthreads();
      }
    }
  } else {
    // pos projection: [2048,512] = posbf(2047 rows, clamped) @ wp^T, 64x64 tiles
    int pid = bid - 768;
    int bx = pid % 8, by = pid / 8;
    int m0 = by*64, n0 = bx*64;
    int wm = wave >> 1, wn = wave & 1;
    f32x4 acc[2][2] = {};
    for(int k0=0; k0<512; k0+=32){
      int rb = wave*16;
      int ra = m0 + rb + srow; if(ra > 2046) ra = 2046;
      gload_lds16(posbf + (size_t)ra*512 + k0 + scol, At + rb*32);
      gload_lds16(wp + (size_t)(n0 + rb + srow)*512 + k0 + scol, Bt + rb*32);
      __syncthreads();
      s16x8 af[2], bfr[2];
      #pragma unroll
      for(int i=0;i<2;i++) af[i]  = *(const s16x8*)(At + (wm*32 + i*16 + l16)*32 + quad*8);
      #pragma unroll
      for(int j=0;j<2;j++) bfr[j] = *(const s16x8*)(Bt + (wn*32 + j*16 + l16)*32 + quad*8);
      #pragma unroll
      for(int i=0;i<2;i++)
        #pragma unroll
        for(int j=0;j<2;j++)
          acc[i][j] = MFMA(af[i], bfr[j], acc[i][j]);
      __syncthreads();
    }
    #pragma unroll
    for(int i=0;i<2;i++){
      int rowb = m0 + wm*32 + i*16 + quad*4;          // rowb&15 = quad*4
      #pragma unroll
      for(int j=0;j<2;j++){
        int col = n0 + wn*32 + j*16 + l16;
        int hh = col>>6, ks = (col>>5)&1, qd = (col>>3)&3, e = col&7;
        int rblk = rowb>>4;
        size_t base = ((size_t)(((hh*128+rblk)*2+ks)*64) + qd*16)*8 + e;
        #pragma unroll
        for(int r=0;r<4;r++)
          p_sw[base + (size_t)(quad*4+r)*8] = f2b(acc[i][j][r]);
      }
    }
  }
}

// ---- Fused rel-pos attention (R13): grid (4,8,8), 512 thr = 8 waves; wave w
// owns 32 q-rows [qt*256 + w*32, +32) as 2 subtiles and iterates all 16 key
// tiles. K+V tiles double-buffered in LDS via global_load_lds (2 loads per
// wave per jt), ONE barrier per jt. Compact XOR-swizzled pw (16x64 per
// subtile, idx ^ ((row&7)<<3); R11-measured conflict-free). Pos fragments
// register-prefetched one jt ahead over the 6-block band union shared by both
// subtiles; K/V fragments reused by both subtiles. Linear (no-max) softmax
// (exact 0.125 fold, __expf); rotated pos-score fed as QK MFMA C-init;
// denominator via ones-splat PV MFMA.
__global__ __launch_bounds__(512, 1) void attn_kernel(
    const short* __restrict__ q_sw, const short* __restrict__ k_sw,
    const short* __restrict__ v_sw, const short* __restrict__ p_sw,
    const float* __restrict__ bu, const float* __restrict__ bvv,
    short* __restrict__ out)
{
  __shared__ __align__(16) short kv[2][8192];   // [buf][units 0..7 = K | 8..15 = V]
  __shared__ __align__(16) short pwall[16384];  // 8 waves x 2 subtiles x swz 16x64
  int tid = threadIdx.x;
  int wave = tid >> 6, lane = tid & 63, quad = lane >> 4, l16 = lane & 15;
  int h = blockIdx.y, b = blockIdx.z, bh = b*8 + h;
  int qt = blockIdx.x;               // 256-row q block
  int iblk32 = qt*8 + wave;          // this wave's 32-row unit (0..31)
  int iw = iblk32*32;
  short* pw = pwall + wave*2048;     // two swizzled 16x64 bf16 P tiles

  const short* qb = q_sw + (size_t)bh*65536;
  const short* kb = k_sw + (size_t)bh*65536;
  const short* vb = v_sw + (size_t)bh*65536;
  const short* pb = p_sw + (size_t)h*131072;

  // q fragments for both subtiles; bias + exact 0.125 scale folded
  s16x8 qu[2][2], qv[2][2];
  #pragma unroll
  for(int s=0;s<2;s++){
    #pragma unroll
    for(int ks=0;ks<2;ks++){
      s16x8 qr = *(const s16x8*)(qb + ((size_t)((iblk32*2+s)*2+ks)*64 + lane)*8);
      short tu[8], tv[8];
      #pragma unroll
      for(int e=0;e<8;e++){
        int d = h*64 + ks*32 + quad*8 + e;
        float f = b2f(qr[e]);
        tu[e] = f2b((f + bu[d]) * 0.125f);
        tv[e] = f2b((f + bvv[d]) * 0.125f);
      }
      qu[s][ks] = *(s16x8*)tu; qv[s][ks] = *(s16x8*)tv;
    }
  }

  // ones splat for the denominator MFMA (bf16 1.0 = 0x3F80)
  s16x8 ones;
  #pragma unroll
  for(int e=0;e<8;e++) ones[e] = (short)0x3F80;

  // hoisted band-gather controls (per accumulator register r; row-in-subtile)
  int srcl[4]; bool lo[4];
  #pragma unroll
  for(int r=0;r<4;r++){
    int il = quad*4 + r;
    srcl[r] = quad*16 + ((l16 + 15 - il) & 15);
    lo[r]   = (l16 <= il);
  }

  f32x4 oacc[2][4] = {};
  f32x4 lacc[2] = {};
  s16x8 Pa[6][2];                    // prefetched pos fragments, 6-block union

  // cooperative K/V stage: unit = wave*2 + r; units 0..7 = K tile, 8..15 = V.
  auto STAGE = [&](int jt, int bufi){
    const short* base = (wave < 4) ? kb : vb;
    #pragma unroll
    for(int r=0;r<2;r++){
      int unit = wave*2 + r;
      gload_lds16(base + (size_t)jt*4096 + (unit&7)*512 + lane*8,
                  &kv[bufi][unit*512]);
    }
  };
  // band union for this wave's 32 rows: subtile0 window rb0..rb0+4,
  // subtile1 window rb0-1..rb0+3; union rb0-1..rb0+4 (6 blocks).
  auto LOADPOS = [&](int jt){
    int rb0 = (jt*64 - iw + 1008) >> 4;
    #pragma unroll
    for(int nt=0;nt<6;nt++)
      #pragma unroll
      for(int ks=0;ks<2;ks++)
        Pa[nt][ks] = *(const s16x8*)(pb + (size_t)((rb0-1+nt)*2+ks)*512 + lane*8);
  };
  auto COMPUTE = [&](const short* Kt, const short* Vt, int next_jt){
    // pos MFMAs consume Pa over the union; then Pa refilled for next_jt.
    f32x4 ps0[5], ps1[5];
    __builtin_amdgcn_s_setprio(1);
    #pragma unroll
    for(int nt=0;nt<6;nt++){
      s16x8 pf0 = Pa[nt][0], pf1 = Pa[nt][1];
      if(nt >= 1){
        f32x4 a = {};
        a = MFMA(qv[0][0], pf0, a);
        a = MFMA(qv[0][1], pf1, a);
        ps0[nt-1] = a;
      }
      if(nt <= 4){
        f32x4 a = {};
        a = MFMA(qv[1][0], pf0, a);
        a = MFMA(qv[1][1], pf1, a);
        ps1[nt] = a;
      }
    }
    __builtin_amdgcn_s_setprio(0);
    if(next_jt < 16) LOADPOS(next_jt);
    // rotate band lanes (both subtiles)
    float rot0[4][5], rot1[4][5];
    #pragma unroll
    for(int r=0;r<4;r++){
      #pragma unroll
      for(int nt=0;nt<5;nt++){
        rot0[r][nt] = __shfl(ps0[nt][r], srcl[r]);
        rot1[r][nt] = __shfl(ps1[nt][r], srcl[r]);
      }
    }
    // content scores with rotated pos-score as C-init; exp; P->LDS (swizzled).
    // K fragments loaded once per js, used by both subtiles.
    #pragma unroll
    for(int js=0;js<4;js++){
      s16x8 kf0 = *(const s16x8*)(Kt + (js*2+0)*512 + lane*8);
      s16x8 kf1 = *(const s16x8*)(Kt + (js*2+1)*512 + lane*8);
      int col = js*16 + l16;
      int r0 = quad*4;
      {
        f32x4 c0;
        #pragma unroll
        for(int r=0;r<4;r++) c0[r] = lo[r] ? rot0[r][js] : rot0[r][js+1];
        f32x4 a = MFMA(qu[0][0], kf0, c0);
        a = MFMA(qu[0][1], kf1, a);
        unsigned p01 = pk2(__expf(a[0]), __expf(a[1]));
        unsigned p23 = pk2(__expf(a[2]), __expf(a[3]));
        pw[((r0+0)*64 + col) ^ (((r0+0)&7)<<3)] = (short)p01;
        pw[((r0+1)*64 + col) ^ (((r0+1)&7)<<3)] = (short)(p01>>16);
        pw[((r0+2)*64 + col) ^ (((r0+2)&7)<<3)] = (short)p23;
        pw[((r0+3)*64 + col) ^ (((r0+3)&7)<<3)] = (short)(p23>>16);
      }
      {
        f32x4 c0;
        #pragma unroll
        for(int r=0;r<4;r++) c0[r] = lo[r] ? rot1[r][js] : rot1[r][js+1];
        f32x4 a = MFMA(qu[1][0], kf0, c0);
        a = MFMA(qu[1][1], kf1, a);
        unsigned p01 = pk2(__expf(a[0]), __expf(a[1]));
        unsigned p23 = pk2(__expf(a[2]), __expf(a[3]));
        pw[1024 + (((r0+0)*64 + col) ^ (((r0+0)&7)<<3))] = (short)p01;
        pw[1024 + (((r0+1)*64 + col) ^ (((r0+1)&7)<<3))] = (short)(p01>>16);
        pw[1024 + (((r0+2)*64 + col) ^ (((r0+2)&7)<<3))] = (short)p23;
        pw[1024 + (((r0+3)*64 + col) ^ (((r0+3)&7)<<3))] = (short)(p23>>16);
      }
    }
    // PV: 2 j-ksteps x (4 d-subtiles + ones row-sum); V fragments shared.
    __builtin_amdgcn_s_setprio(1);
    #pragma unroll
    for(int jk=0;jk<2;jk++){
      int po = (l16*64 + jk*32 + quad*8) ^ ((l16&7)<<3);
      s16x8 pa0 = *(const s16x8*)(pw + po);
      s16x8 pa1 = *(const s16x8*)(pw + 1024 + po);
      lacc[0] = MFMA(pa0, ones, lacc[0]);
      lacc[1] = MFMA(pa1, ones, lacc[1]);
      #pragma unroll
      for(int ds=0;ds<4;ds++){
        s16x8 vf = *(const s16x8*)(Vt + (ds*2+jk)*512 + lane*8);
        oacc[0][ds] = MFMA(pa0, vf, oacc[0][ds]);
        oacc[1][ds] = MFMA(pa1, vf, oacc[1][ds]);
      }
    }
    __builtin_amdgcn_s_setprio(0);
  };

  // prologue: stage jt=0, load pos jt=0
  STAGE(0, 0);
  LOADPOS(0);
  __syncthreads();                       // drains stage(0) (+ pos loads)

  #pragma unroll 1
  for(int jt2=0; jt2<8; ++jt2){
    int jt = jt2*2;
    // even phase: compute from buf0, stage jt+1 into buf1
    STAGE(jt+1, 1);
    COMPUTE(&kv[0][0], &kv[0][4096], jt+1);
    __syncthreads();                     // stage(jt+1) drained (had full compute to land)
    // odd phase: compute from buf1, stage jt+2 into buf0
    if(jt2 < 7) STAGE(jt+2, 0);
    COMPUTE(&kv[1][0], &kv[1][4096], jt+2);
    __syncthreads();
  }

  // epilogue: wave owns its rows end-to-end; write bf16 attn output directly
  #pragma unroll
  for(int s=0;s<2;s++){
    float rl[4];
    #pragma unroll
    for(int r=0;r<4;r++) rl[r] = __builtin_amdgcn_rcpf(lacc[s][r]);
    #pragma unroll
    for(int ds=0; ds<4; ds++)
      #pragma unroll
      for(int r=0;r<4;r++)
        out[((size_t)(b*1024 + iw + s*16 + quad*4 + r))*512 + h*64 + ds*16 + l16] =
            f2b(oacc[s][ds][r] * rl[r]);
  }
}

// ---- out projection (R13): fp32 out = a_bf @ Wo^T + bo + x, 128x128 tiles
// (gemm_fused's proven k-loop: 16 MFMA/wave/step, 8 gload_lds/step), 256 blocks.
__global__ __launch_bounds__(256) void gemm_out(
    const short* __restrict__ A, const short* __restrict__ B,
    const float* __restrict__ bias, const float* __restrict__ resid,
    float* __restrict__ Cout)
{
  __shared__ __align__(16) short At[128*32];
  __shared__ __align__(16) short Bt[128*32];
  int tid = threadIdx.x;
  int wave = tid >> 6, lane = tid & 63;
  int quad = lane >> 4, l16 = lane & 15;
  int wm = wave >> 1, wn = wave & 1;
  int m0 = blockIdx.y*128, n0 = blockIdx.x*128;
  int srow = lane >> 2, scol = (lane & 3)*8;
  f32x4 acc[4][4] = {};
  for(int k0=0; k0<512; k0+=32){
    #pragma unroll
    for(int c=0;c<2;c++){
      int rb = (wave + 4*c)*16;
      gload_lds16(A + (size_t)(m0 + rb + srow)*512 + k0 + scol, At + rb*32);
      gload_lds16(B + (size_t)(n0 + rb + srow)*512 + k0 + scol, Bt + rb*32);
    }
    __syncthreads();
    s16x8 af[4], bfr[4];
    #pragma unroll
    for(int i=0;i<4;i++) af[i]  = *(const s16x8*)(At + (wm*64 + i*16 + l16)*32 + quad*8);
    #pragma unroll
    for(int j=0;j<4;j++) bfr[j] = *(const s16x8*)(Bt + (wn*64 + j*16 + l16)*32 + quad*8);
    #pragma unroll
    for(int i=0;i<4;i++)
      #pragma unroll
      for(int j=0;j<4;j++)
        acc[i][j] = MFMA(af[i], bfr[j], acc[i][j]);
    __syncthreads();
  }
  #pragma unroll
  for(int i=0;i<4;i++){
    int rowb = m0 + wm*64 + i*16 + quad*4;
    #pragma unroll
    for(int j=0;j<4;j++){
      int col = n0 + wn*64 + j*16 + l16;
      float bv = bias[col];
      #pragma unroll
      for(int r=0;r<4;r++){
        size_t idx = (size_t)(rowb + r)*512 + col;
        Cout[idx] = acc[i][j][r] + bv + resid[idx];
      }
    }
  }
}

extern "C" void kernel_launch(void* const* d_in, const int* in_sizes, int n_in,
                              void* d_out, int out_size, void* d_ws, size_t ws_size,
                              hipStream_t stream)
{
  const float* x    = (const float*)d_in[0];
  const float* pos  = (const float*)d_in[1];
  const float* lnw  = (const float*)d_in[2];
  const float* lnb  = (const float*)d_in[3];
  const float* Wq   = (const float*)d_in[4];
  const float* bq   = (const float*)d_in[5];
  const float* Wk   = (const float*)d_in[6];
  const float* bk   = (const float*)d_in[7];
  const float* Wv   = (const float*)d_in[8];
  const float* bv   = (const float*)d_in[9];
  const float* Wo   = (const float*)d_in[10];
  const float* bo   = (const float*)d_in[11];
  const float* Wp   = (const float*)d_in[12];
  const float* pbu  = (const float*)d_in[13];
  const float* pbv  = (const float*)d_in[14];
  float* out = (float*)d_out;

  char* ws = (char*)d_ws;
  short* h_bf    = (short*)(ws);                 // 8192x512
  short* q_sw    = (short*)(ws + ( 8u<<20));     // fragment-major
  short* k_sw    = (short*)(ws + (16u<<20));
  short* v_sw    = (short*)(ws + (24u<<20));
  short* a_bf    = (short*)(ws + (32u<<20));     // attn out, row-major
  short* p_sw    = (short*)(ws + (40u<<20));     // 2 MB
  short* pos_bf  = (short*)(ws + (42u<<20));     // 2 MB
  short* wqkv_bf = (short*)(ws + (44u<<20));     // 3 MB
  short* wo_bf   = (short*)(ws + (47u<<20));     // 0.5 MB
  short* wp_bf   = (short*)(ws + (47u<<20) + (512u<<10));

  prep_kernel<<<dim3(3200), 256, 0, stream>>>(Wq, Wk, Wv, Wo, Wp, pos,
                                              x, lnw, lnb,
                                              wqkv_bf, wo_bf, wp_bf, pos_bf, h_bf);
  gemm_fused<<<dim3(1024), 256, 0, stream>>>(h_bf, wqkv_bf, bq, bk, bv,
                                             pos_bf, wp_bf,
                                             q_sw, k_sw, v_sw, p_sw);
  attn_kernel<<<dim3(4,8,8), 512, 0, stream>>>(q_sw, k_sw, v_sw, p_sw, pbu, pbv, a_bf);
  gemm_out<<<dim3(4,64), 256, 0, stream>>>(a_bf, wo_bf, bo, x, out);
  (void)in_sizes; (void)n_in; (void)out_size; (void)ws_size;
}

// Round 7
// 191.515 us; speedup vs baseline: 1.1356x; 1.0065x over previous
//
#include <hip/hip_runtime.h>
#include <hip/hip_bf16.h>

// ConformerAttention on MI355X (gfx950), bf16 MFMA internal, fp32 in/out.
// rel_shift(ps)[i,j] == ps[i, j-i+S-1]  -> banded pos-score, never materialize [S,P].
// R14: attn — cut DS-pipe pressure: P stores 64x ds_write_b16 -> 16x ds_write_b32
//      per wave/jt via DPP quad_perm lane-pairing (VALU) + row-major u32 merges,
//      same XOR-swizzled pw layout as the PV read (bit-identical math).
//      DS ops/wave/jt 124 -> 76. Rest identical to R13.

typedef __attribute__((ext_vector_type(8))) short  s16x8;
typedef __attribute__((ext_vector_type(8))) __bf16 bfv8;
typedef __attribute__((ext_vector_type(4))) float  f32x4;
typedef __attribute__((ext_vector_type(4))) unsigned u32x4;

__device__ __forceinline__ float b2f(short s){
  unsigned u = ((unsigned)(unsigned short)s) << 16;
  float f; __builtin_memcpy(&f, &u, 4); return f;
}
__device__ __forceinline__ short f2b(float f){
  unsigned u; __builtin_memcpy(&u, &f, 4);
  u = (u + 0x7fffu + ((u >> 16) & 1u)) >> 16;
  return (short)u;
}
// packed 2xf32 -> 2xbf16 (v_cvt_pk_bf16_f32 on gfx950), low = first arg
__device__ __forceinline__ unsigned pk2(float lo, float hi){
  __hip_bfloat162 t = __float22bfloat162_rn(make_float2(lo, hi));
  unsigned u; __builtin_memcpy(&u, &t, 4); return u;
}
__device__ __forceinline__ f32x4 MFMA(s16x8 a, s16x8 b, f32x4 c){
  return __builtin_amdgcn_mfma_f32_16x16x32_bf16(
      __builtin_bit_cast(bfv8, a), __builtin_bit_cast(bfv8, b), c, 0, 0, 0);
}
__device__ __forceinline__ void gload_lds16(const void* g, void* l){
  __builtin_amdgcn_global_load_lds(
      (const __attribute__((address_space(1))) void*)g,
      (__attribute__((address_space(3))) void*)l, 16, 0, 0);
}
// lane^1 exchange on the VALU pipe (DPP quad_perm [1,0,3,2]), not DS.
__device__ __forceinline__ unsigned dpp_xor1(unsigned v){
  return (unsigned)__builtin_amdgcn_update_dpp(0, (int)v, 0xB1, 0xF, 0xF, true);
}
__device__ __forceinline__ void cvt8(const float* in, short* out, size_t i8){
  f32x4 a = *(const f32x4*)(in + i8*8);
  f32x4 b = *(const f32x4*)(in + i8*8 + 4);
  u32x4 o;
  o[0] = pk2(a[0],a[1]); o[1] = pk2(a[2],a[3]);
  o[2] = pk2(b[0],b[1]); o[3] = pk2(b[2],b[3]);
  *(u32x4*)(out + i8*8) = o;
}

// ---- prep: weight/pos converts + LayerNorm, one launch ----
__global__ __launch_bounds__(256) void prep_kernel(
    const float* __restrict__ Wq, const float* __restrict__ Wk,
    const float* __restrict__ Wv, const float* __restrict__ Wo,
    const float* __restrict__ Wp, const float* __restrict__ pos,
    const float* __restrict__ x, const float* __restrict__ lnw, const float* __restrict__ lnb,
    short* __restrict__ wqkv, short* __restrict__ wo, short* __restrict__ wp,
    short* __restrict__ posbf, short* __restrict__ h_bf)
{
  int bid = blockIdx.x, tid = threadIdx.x;
  if(bid < 640){
    int w = bid >> 7;
    size_t i = (size_t)(bid & 127)*256 + tid;
    const float* src; short* dst;
    if(w == 0){ src = Wq; dst = wqkv; }
    else if(w == 1){ src = Wk; dst = wqkv + 262144; }
    else if(w == 2){ src = Wv; dst = wqkv + 524288; }
    else if(w == 3){ src = Wo; dst = wo; }
    else { src = Wp; dst = wp; }
    cvt8(src, dst, i);
  } else if(bid < 1152){
    size_t i = (size_t)(bid - 640)*256 + tid;
    if(i < 131008) cvt8(pos, posbf, i);        // 2047*512/8
  } else {
    int row = (bid - 1152)*4 + (tid >> 6);
    int lane = tid & 63;
    const float* xr = x + (size_t)row*512;
    f32x4 v0 = *(const f32x4*)(xr + lane*8);
    f32x4 v1 = *(const f32x4*)(xr + lane*8 + 4);
    float s  = v0[0]+v0[1]+v0[2]+v0[3]+v1[0]+v1[1]+v1[2]+v1[3];
    float s2 = v0[0]*v0[0]+v0[1]*v0[1]+v0[2]*v0[2]+v0[3]*v0[3]
             + v1[0]*v1[0]+v1[1]*v1[1]+v1[2]*v1[2]+v1[3]*v1[3];
    #pragma unroll
    for(int m=1;m<64;m<<=1){ s += __shfl_xor(s,m); s2 += __shfl_xor(s2,m); }
    float mu = s * (1.0f/512.0f);
    float rs = rsqrtf(s2*(1.0f/512.0f) - mu*mu + 1e-5f);
    float y[8];
    #pragma unroll
    for(int e=0;e<8;e++){
      float xv = (e<4)? v0[e] : v1[e-4];
      int d = lane*8 + e;
      y[e] = (xv - mu)*rs*lnw[d] + lnb[d];
    }
    u32x4 o;
    o[0]=pk2(y[0],y[1]); o[1]=pk2(y[2],y[3]); o[2]=pk2(y[4],y[5]); o[3]=pk2(y[6],y[7]);
    *(u32x4*)(h_bf + (size_t)row*512 + lane*8) = o;
  }
}

// ---- fused QKV GEMM (768 blocks, 128x128) + pos GEMM (256 blocks, 64x64) ----
__global__ __launch_bounds__(256) void gemm_fused(
    const short* __restrict__ h_bf, const short* __restrict__ wqkv,
    const float* __restrict__ bq, const float* __restrict__ bk, const float* __restrict__ bv,
    const short* __restrict__ posbf, const short* __restrict__ wp,
    short* __restrict__ q_sw, short* __restrict__ k_sw, short* __restrict__ v_sw,
    short* __restrict__ p_sw)
{
  __shared__ __align__(16) short smem[9216];   // At|Bt staging, then C-tile staging
  short* At = smem;
  short* Bt = smem + 4096;
  int bid = blockIdx.x, tid = threadIdx.x;
  int wave = tid >> 6, lane = tid & 63;
  int quad = lane >> 4, l16 = lane & 15;
  int srow = lane >> 2, scol = (lane & 3)*8;
  if(bid < 768){
    int bx = bid % 12, by = bid / 12;
    int m0 = by*128, n0 = bx*128;
    int wm = wave >> 1, wn = wave & 1;
    f32x4 acc[4][4] = {};
    for(int k0=0; k0<512; k0+=32){
      #pragma unroll
      for(int c=0;c<2;c++){
        int rb = (wave + 4*c)*16;
        gload_lds16(h_bf + (size_t)(m0 + rb + srow)*512 + k0 + scol, At + rb*32);
        gload_lds16(wqkv + (size_t)(n0 + rb + srow)*512 + k0 + scol, Bt + rb*32);
      }
      __syncthreads();
      s16x8 af[4], bfr[4];
      #pragma unroll
      for(int i=0;i<4;i++) af[i]  = *(const s16x8*)(At + (wm*64 + i*16 + l16)*32 + quad*8);
      #pragma unroll
      for(int j=0;j<4;j++) bfr[j] = *(const s16x8*)(Bt + (wn*64 + j*16 + l16)*32 + quad*8);
      #pragma unroll
      for(int i=0;i<4;i++)
        #pragma unroll
        for(int j=0;j<4;j++)
          acc[i][j] = MFMA(af[i], bfr[j], acc[i][j]);
      __syncthreads();
    }
    int seg = bx >> 2;               // 0 q, 1 k, 2 v (uniform per block)
    int nseg = (bx & 3)*128;
    int bb = by >> 3;
    const float* bsrc = (seg==0)? bq : (seg==1)? bk : bv;
    float bias_j[4];
    #pragma unroll
    for(int j=0;j<4;j++) bias_j[j] = bsrc[nseg + wn*64 + j*16 + l16];
    if(seg < 2){
      short* dst = seg ? k_sw : q_sw;
      #pragma unroll
      for(int h2=0; h2<2; h2++){
        if(wm == h2){
          #pragma unroll
          for(int i=0;i<4;i++){
            int lr = i*16 + quad*4;
            #pragma unroll
            for(int j=0;j<4;j++){
              int cl = wn*64 + j*16 + l16;
              unsigned p01 = pk2(acc[i][j][0]+bias_j[j], acc[i][j][1]+bias_j[j]);
              unsigned p23 = pk2(acc[i][j][2]+bias_j[j], acc[i][j][3]+bias_j[j]);
              smem[(lr+0)*136 + cl] = (short)p01;
              smem[(lr+1)*136 + cl] = (short)(p01>>16);
              smem[(lr+2)*136 + cl] = (short)p23;
              smem[(lr+3)*136 + cl] = (short)(p23>>16);
            }
          }
        }
        __syncthreads();
        #pragma unroll
        for(int it=0; it<4; it++){
          int ci = it*4 + wave;              // hs = ci>>2 (head/ks slot), tb = ci&3
          int hs = ci >> 2, tb = ci & 3;
          s16x8 vv = *(const s16x8*)(smem + (tb*16 + l16)*136 + hs*32 + quad*8);
          int hh = (nseg>>6) + (hs>>1);
          int tg = ((m0 + h2*64)>>4) + tb;
          size_t chunk = ((size_t)((bb*8 + hh)*64 + tg))*2 + (hs&1);
          *(s16x8*)(dst + chunk*512 + (size_t)lane*8) = vv;
        }
        __syncthreads();
      }
    } else {
      // V: stage transposed Ct_v[dim 0..127][token 0..63], stride 72
      #pragma unroll
      for(int h2=0; h2<2; h2++){
        int jt = by*2 + h2;
        if(wm == h2){
          #pragma unroll
          for(int i=0;i<4;i++){
            int tl = i*16 + quad*4;
            #pragma unroll
            for(int j=0;j<4;j++){
              int dl = wn*64 + j*16 + l16;
              unsigned p01 = pk2(acc[i][j][0]+bias_j[j], acc[i][j][1]+bias_j[j]);
              unsigned p23 = pk2(acc[i][j][2]+bias_j[j], acc[i][j][3]+bias_j[j]);
              unsigned* w2 = (unsigned*)(smem + dl*72 + tl);
              w2[0] = p01; w2[1] = p23;
            }
          }
        }
        __syncthreads();
        #pragma unroll
        for(int it=0; it<4; it++){
          int ci = it*4 + wave;              // ci = hl*8 + ds*2 + jk
          int hl = ci>>3, ds = (ci>>1)&3, jk = ci&1;
          s16x8 vv = *(const s16x8*)(smem + (hl*64 + ds*16 + l16)*72 + jk*32 + quad*8);
          int hh = (nseg>>6) + hl;
          size_t chunk = (((size_t)((bb*8 + hh)*16 + jt))*4 + ds)*2 + jk;
          *(s16x8*)(v_sw + chunk*512 + (size_t)lane*8) = vv;
        }
        __syncthreads();
      }
    }
  } else {
    // pos projection: [2048,512] = posbf(2047 rows, clamped) @ wp^T, 64x64 tiles
    int pid = bid - 768;
    int bx = pid % 8, by = pid / 8;
    int m0 = by*64, n0 = bx*64;
    int wm = wave >> 1, wn = wave & 1;
    f32x4 acc[2][2] = {};
    for(int k0=0; k0<512; k0+=32){
      int rb = wave*16;
      int ra = m0 + rb + srow; if(ra > 2046) ra = 2046;
      gload_lds16(posbf + (size_t)ra*512 + k0 + scol, At + rb*32);
      gload_lds16(wp + (size_t)(n0 + rb + srow)*512 + k0 + scol, Bt + rb*32);
      __syncthreads();
      s16x8 af[2], bfr[2];
      #pragma unroll
      for(int i=0;i<2;i++) af[i]  = *(const s16x8*)(At + (wm*32 + i*16 + l16)*32 + quad*8);
      #pragma unroll
      for(int j=0;j<2;j++) bfr[j] = *(const s16x8*)(Bt + (wn*32 + j*16 + l16)*32 + quad*8);
      #pragma unroll
      for(int i=0;i<2;i++)
        #pragma unroll
        for(int j=0;j<2;j++)
          acc[i][j] = MFMA(af[i], bfr[j], acc[i][j]);
      __syncthreads();
    }
    #pragma unroll
    for(int i=0;i<2;i++){
      int rowb = m0 + wm*32 + i*16 + quad*4;          // rowb&15 = quad*4
      #pragma unroll
      for(int j=0;j<2;j++){
        int col = n0 + wn*32 + j*16 + l16;
        int hh = col>>6, ks = (col>>5)&1, qd = (col>>3)&3, e = col&7;
        int rblk = rowb>>4;
        size_t base = ((size_t)(((hh*128+rblk)*2+ks)*64) + qd*16)*8 + e;
        #pragma unroll
        for(int r=0;r<4;r++)
          p_sw[base + (size_t)(quad*4+r)*8] = f2b(acc[i][j][r]);
      }
    }
  }
}

// ---- Fused rel-pos attention (R14): grid (4,8,8), 512 thr = 8 waves; wave w
// owns 32 q-rows [qt*256 + w*32, +32) as 2 subtiles and iterates all 16 key
// tiles. K+V tiles double-buffered in LDS via global_load_lds (2 loads per
// wave per jt), ONE barrier per jt. Compact XOR-swizzled pw; P stores via DPP
// lane-pairing -> 2x ds_write_b32 per js/subtile (was 8x ds_write_b16). Pos
// fragments register-prefetched one jt ahead over the 6-block band union.
// Linear (no-max) softmax (exact 0.125 fold, __expf); rotated pos-score fed
// as QK MFMA C-init; denominator via ones-splat PV MFMA.
__global__ __launch_bounds__(512, 1) void attn_kernel(
    const short* __restrict__ q_sw, const short* __restrict__ k_sw,
    const short* __restrict__ v_sw, const short* __restrict__ p_sw,
    const float* __restrict__ bu, const float* __restrict__ bvv,
    short* __restrict__ out)
{
  __shared__ __align__(16) short kv[2][8192];   // [buf][units 0..7 = K | 8..15 = V]
  __shared__ __align__(16) short pwall[16384];  // 8 waves x 2 subtiles x swz 16x64
  int tid = threadIdx.x;
  int wave = tid >> 6, lane = tid & 63, quad = lane >> 4, l16 = lane & 15;
  int h = blockIdx.y, b = blockIdx.z, bh = b*8 + h;
  int qt = blockIdx.x;               // 256-row q block
  int iblk32 = qt*8 + wave;          // this wave's 32-row unit (0..31)
  int iw = iblk32*32;
  short* pw = pwall + wave*2048;     // two swizzled 16x64 bf16 P tiles

  const short* qb = q_sw + (size_t)bh*65536;
  const short* kb = k_sw + (size_t)bh*65536;
  const short* vb = v_sw + (size_t)bh*65536;
  const short* pb = p_sw + (size_t)h*131072;

  // q fragments for both subtiles; bias + exact 0.125 scale folded
  s16x8 qu[2][2], qv[2][2];
  #pragma unroll
  for(int s=0;s<2;s++){
    #pragma unroll
    for(int ks=0;ks<2;ks++){
      s16x8 qr = *(const s16x8*)(qb + ((size_t)((iblk32*2+s)*2+ks)*64 + lane)*8);
      short tu[8], tv[8];
      #pragma unroll
      for(int e=0;e<8;e++){
        int d = h*64 + ks*32 + quad*8 + e;
        float f = b2f(qr[e]);
        tu[e] = f2b((f + bu[d]) * 0.125f);
        tv[e] = f2b((f + bvv[d]) * 0.125f);
      }
      qu[s][ks] = *(s16x8*)tu; qv[s][ks] = *(s16x8*)tv;
    }
  }

  // ones splat for the denominator MFMA (bf16 1.0 = 0x3F80)
  s16x8 ones;
  #pragma unroll
  for(int e=0;e<8;e++) ones[e] = (short)0x3F80;

  // hoisted band-gather controls (per accumulator register r; row-in-subtile)
  int srcl[4]; bool lo[4];
  #pragma unroll
  for(int r=0;r<4;r++){
    int il = quad*4 + r;
    srcl[r] = quad*16 + ((l16 + 15 - il) & 15);
    lo[r]   = (l16 <= il);
  }

  f32x4 oacc[2][4] = {};
  f32x4 lacc[2] = {};
  s16x8 Pa[6][2];                    // prefetched pos fragments, 6-block union
  int parity = l16 & 1;

  // cooperative K/V stage: unit = wave*2 + r; units 0..7 = K tile, 8..15 = V.
  auto STAGE = [&](int jt, int bufi){
    const short* base = (wave < 4) ? kb : vb;
    #pragma unroll
    for(int r=0;r<2;r++){
      int unit = wave*2 + r;
      gload_lds16(base + (size_t)jt*4096 + (unit&7)*512 + lane*8,
                  &kv[bufi][unit*512]);
    }
  };
  // band union for this wave's 32 rows: subtile0 window rb0..rb0+4,
  // subtile1 window rb0-1..rb0+3; union rb0-1..rb0+4 (6 blocks).
  auto LOADPOS = [&](int jt){
    int rb0 = (jt*64 - iw + 1008) >> 4;
    #pragma unroll
    for(int nt=0;nt<6;nt++)
      #pragma unroll
      for(int ks=0;ks<2;ks++)
        Pa[nt][ks] = *(const s16x8*)(pb + (size_t)((rb0-1+nt)*2+ks)*512 + lane*8);
  };
  // P store: pack (rows r..r+1) x (cols c,c+1) as u32 row-pairs via DPP xor-1
  // (VALU) and write 2x ds_write_b32 through the read-side XOR swizzle.
  auto PSTORE = [&](short* pwb, unsigned p01, unsigned p23, int cp){
    unsigned n01 = dpp_xor1(p01), n23 = dpp_xor1(p23);
    unsigned lowsrc  = parity ? n23 : p01;
    unsigned highsrc = parity ? p23 : n01;
    unsigned ua = (lowsrc & 0xFFFFu) | (highsrc << 16);
    unsigned ub = (lowsrc >> 16) | (highsrc & 0xFFFF0000u);
    int rowA = quad*4 + 2*parity;
    *(unsigned*)(pwb + (((rowA  )*64 + cp) ^ (((rowA  )&7)<<3))) = ua;
    *(unsigned*)(pwb + (((rowA+1)*64 + cp) ^ (((rowA+1)&7)<<3))) = ub;
  };
  auto COMPUTE = [&](const short* Kt, const short* Vt, int next_jt){
    // pos MFMAs consume Pa over the union; then Pa refilled for next_jt.
    f32x4 ps0[5], ps1[5];
    __builtin_amdgcn_s_setprio(1);
    #pragma unroll
    for(int nt=0;nt<6;nt++){
      s16x8 pf0 = Pa[nt][0], pf1 = Pa[nt][1];
      if(nt >= 1){
        f32x4 a = {};
        a = MFMA(qv[0][0], pf0, a);
        a = MFMA(qv[0][1], pf1, a);
        ps0[nt-1] = a;
      }
      if(nt <= 4){
        f32x4 a = {};
        a = MFMA(qv[1][0], pf0, a);
        a = MFMA(qv[1][1], pf1, a);
        ps1[nt] = a;
      }
    }
    __builtin_amdgcn_s_setprio(0);
    if(next_jt < 16) LOADPOS(next_jt);
    // rotate band lanes (both subtiles)
    float rot0[4][5], rot1[4][5];
    #pragma unroll
    for(int r=0;r<4;r++){
      #pragma unroll
      for(int nt=0;nt<5;nt++){
        rot0[r][nt] = __shfl(ps0[nt][r], srcl[r]);
        rot1[r][nt] = __shfl(ps1[nt][r], srcl[r]);
      }
    }
    // content scores with rotated pos-score as C-init; exp; P->LDS (swizzled).
    // K fragments loaded once per js, used by both subtiles.
    #pragma unroll
    for(int js=0;js<4;js++){
      s16x8 kf0 = *(const s16x8*)(Kt + (js*2+0)*512 + lane*8);
      s16x8 kf1 = *(const s16x8*)(Kt + (js*2+1)*512 + lane*8);
      int cp = (js*16 + l16) & ~1;
      {
        f32x4 c0;
        #pragma unroll
        for(int r=0;r<4;r++) c0[r] = lo[r] ? rot0[r][js] : rot0[r][js+1];
        f32x4 a = MFMA(qu[0][0], kf0, c0);
        a = MFMA(qu[0][1], kf1, a);
        unsigned p01 = pk2(__expf(a[0]), __expf(a[1]));
        unsigned p23 = pk2(__expf(a[2]), __expf(a[3]));
        PSTORE(pw, p01, p23, cp);
      }
      {
        f32x4 c0;
        #pragma unroll
        for(int r=0;r<4;r++) c0[r] = lo[r] ? rot1[r][js] : rot1[r][js+1];
        f32x4 a = MFMA(qu[1][0], kf0, c0);
        a = MFMA(qu[1][1], kf1, a);
        unsigned p01 = pk2(__expf(a[0]), __expf(a[1]));
        unsigned p23 = pk2(__expf(a[2]), __expf(a[3]));
        PSTORE(pw + 1024, p01, p23, cp);
      }
    }
    // PV: 2 j-ksteps x (4 d-subtiles + ones row-sum); V fragments shared.
    __builtin_amdgcn_s_setprio(1);
    #pragma unroll
    for(int jk=0;jk<2;jk++){
      int po = (l16*64 + jk*32 + quad*8) ^ ((l16&7)<<3);
      s16x8 pa0 = *(const s16x8*)(pw + po);
      s16x8 pa1 = *(const s16x8*)(pw + 1024 + po);
      lacc[0] = MFMA(pa0, ones, lacc[0]);
      lacc[1] = MFMA(pa1, ones, lacc[1]);
      #pragma unroll
      for(int ds=0;ds<4;ds++){
        s16x8 vf = *(const s16x8*)(Vt + (ds*2+jk)*512 + lane*8);
        oacc[0][ds] = MFMA(pa0, vf, oacc[0][ds]);
        oacc[1][ds] = MFMA(pa1, vf, oacc[1][ds]);
      }
    }
    __builtin_amdgcn_s_setprio(0);
  };

  // prologue: stage jt=0, load pos jt=0
  STAGE(0, 0);
  LOADPOS(0);
  __syncthreads();                       // drains stage(0) (+ pos loads)

  #pragma unroll 1
  for(int jt2=0; jt2<8; ++jt2){
    int jt = jt2*2;
    // even phase: compute from buf0, stage jt+1 into buf1
    STAGE(jt+1, 1);
    COMPUTE(&kv[0][0], &kv[0][4096], jt+1);
    __syncthreads();                     // stage(jt+1) drained (had full compute to land)
    // odd phase: compute from buf1, stage jt+2 into buf0
    if(jt2 < 7) STAGE(jt+2, 0);
    COMPUTE(&kv[1][0], &kv[1][4096], jt+2);
    __syncthreads();
  }

  // epilogue: wave owns its rows end-to-end; write bf16 attn output directly
  #pragma unroll
  for(int s=0;s<2;s++){
    float rl[4];
    #pragma unroll
    for(int r=0;r<4;r++) rl[r] = __builtin_amdgcn_rcpf(lacc[s][r]);
    #pragma unroll
    for(int ds=0; ds<4; ds++)
      #pragma unroll
      for(int r=0;r<4;r++)
        out[((size_t)(b*1024 + iw + s*16 + quad*4 + r))*512 + h*64 + ds*16 + l16] =
            f2b(oacc[s][ds][r] * rl[r]);
  }
}

// ---- out projection (R13): fp32 out = a_bf @ Wo^T + bo + x, 128x128 tiles
// (gemm_fused's proven k-loop: 16 MFMA/wave/step, 8 gload_lds/step), 256 blocks.
__global__ __launch_bounds__(256) void gemm_out(
    const short* __restrict__ A, const short* __restrict__ B,
    const float* __restrict__ bias, const float* __restrict__ resid,
    float* __restrict__ Cout)
{
  __shared__ __align__(16) short At[128*32];
  __shared__ __align__(16) short Bt[128*32];
  int tid = threadIdx.x;
  int wave = tid >> 6, lane = tid & 63;
  int quad = lane >> 4, l16 = lane & 15;
  int wm = wave >> 1, wn = wave & 1;
  int m0 = blockIdx.y*128, n0 = blockIdx.x*128;
  int srow = lane >> 2, scol = (lane & 3)*8;
  f32x4 acc[4][4] = {};
  for(int k0=0; k0<512; k0+=32){
    #pragma unroll
    for(int c=0;c<2;c++){
      int rb = (wave + 4*c)*16;
      gload_lds16(A + (size_t)(m0 + rb + srow)*512 + k0 + scol, At + rb*32);
      gload_lds16(B + (size_t)(n0 + rb + srow)*512 + k0 + scol, Bt + rb*32);
    }
    __syncthreads();
    s16x8 af[4], bfr[4];
    #pragma unroll
    for(int i=0;i<4;i++) af[i]  = *(const s16x8*)(At + (wm*64 + i*16 + l16)*32 + quad*8);
    #pragma unroll
    for(int j=0;j<4;j++) bfr[j] = *(const s16x8*)(Bt + (wn*64 + j*16 + l16)*32 + quad*8);
    #pragma unroll
    for(int i=0;i<4;i++)
      #pragma unroll
      for(int j=0;j<4;j++)
        acc[i][j] = MFMA(af[i], bfr[j], acc[i][j]);
    __syncthreads();
  }
  #pragma unroll
  for(int i=0;i<4;i++){
    int rowb = m0 + wm*64 + i*16 + quad*4;
    #pragma unroll
    for(int j=0;j<4;j++){
      int col = n0 + wn*64 + j*16 + l16;
      float bv = bias[col];
      #pragma unroll
      for(int r=0;r<4;r++){
        size_t idx = (size_t)(rowb + r)*512 + col;
        Cout[idx] = acc[i][j][r] + bv + resid[idx];
      }
    }
  }
}

extern "C" void kernel_launch(void* const* d_in, const int* in_sizes, int n_in,
                              void* d_out, int out_size, void* d_ws, size_t ws_size,
                              hipStream_t stream)
{
  const float* x    = (const float*)d_in[0];
  const float* pos  = (const float*)d_in[1];
  const float* lnw  = (const float*)d_in[2];
  const float* lnb  = (const float*)d_in[3];
  const float* Wq   = (const float*)d_in[4];
  const float* bq   = (const float*)d_in[5];
  const float* Wk   = (const float*)d_in[6];
  const float* bk   = (const float*)d_in[7];
  const float* Wv   = (const float*)d_in[8];
  const float* bv   = (const float*)d_in[9];
  const float* Wo   = (const float*)d_in[10];
  const float* bo   = (const float*)d_in[11];
  const float* Wp   = (const float*)d_in[12];
  const float* pbu  = (const float*)d_in[13];
  const float* pbv  = (const float*)d_in[14];
  float* out = (float*)d_out;

  char* ws = (char*)d_ws;
  short* h_bf    = (short*)(ws);                 // 8192x512
  short* q_sw    = (short*)(ws + ( 8u<<20));     // fragment-major
  short* k_sw    = (short*)(ws + (16u<<20));
  short* v_sw    = (short*)(ws + (24u<<20));
  short* a_bf    = (short*)(ws + (32u<<20));     // attn out, row-major
  short* p_sw    = (short*)(ws + (40u<<20));     // 2 MB
  short* pos_bf  = (short*)(ws + (42u<<20));     // 2 MB
  short* wqkv_bf = (short*)(ws + (44u<<20));     // 3 MB
  short* wo_bf   = (short*)(ws + (47u<<20));     // 0.5 MB
  short* wp_bf   = (short*)(ws + (47u<<20) + (512u<<10));

  prep_kernel<<<dim3(3200), 256, 0, stream>>>(Wq, Wk, Wv, Wo, Wp, pos,
                                              x, lnw, lnb,
                                              wqkv_bf, wo_bf, wp_bf, pos_bf, h_bf);
  gemm_fused<<<dim3(1024), 256, 0, stream>>>(h_bf, wqkv_bf, bq, bk, bv,
                                             pos_bf, wp_bf,
                                             q_sw, k_sw, v_sw, p_sw);
  attn_kernel<<<dim3(4,8,8), 512, 0, stream>>>(q_sw, k_sw, v_sw, p_sw, pbu, pbv, a_bf);
  gemm_out<<<dim3(4,64), 256, 0, stream>>>(a_bf, wo_bf, bo, x, out);
  (void)in_sizes; (void)n_in; (void)out_size; (void)ws_size;
}